// Round 1
// baseline (1214.680 us; speedup 1.0000x reference)
//
#include <hip/hip_runtime.h>

#define N_ATOMS 4096
#define T_TOK   512
#define NWQ     32
#define NHK     128
#define KWIN    128      // N_ATOMS / NWQ
#define ATOM_S  128
#define ATOM_Z  16
#define TOKEN_S 384
#define TOKEN_Z 128
#define FEATD   388

// ---------------------------------------------------------------------------
// Kernel 1: extract token index per atom from one-hot atom_to_token [N, T]
// one wave per atom; 4 atoms per 256-thread block
// ---------------------------------------------------------------------------
__global__ __launch_bounds__(256) void tok_kernel(const float* __restrict__ a2t,
                                                  int* __restrict__ tok) {
    const int wave = threadIdx.x >> 6;
    const int lane = threadIdx.x & 63;
    const int n = blockIdx.x * 4 + wave;
    if (n >= N_ATOMS) return;
    const float* row = a2t + (size_t)n * T_TOK;
    int found = 0;
#pragma unroll
    for (int m = 0; m < T_TOK / 64; ++m) {
        float v = row[lane + 64 * m];
        if (v > 0.5f) found = lane + 64 * m;
    }
#pragma unroll
    for (int off = 32; off >= 1; off >>= 1)
        found = max(found, __shfl_xor(found, off, 64));
    if (lane == 0) tok[n] = found;
}

// ---------------------------------------------------------------------------
// Kernel 2: c0 = atom_feats @ W_feat + b_feat  -> q output [N, 128]
// block = 128 threads (one output dim each), 16 atoms per block
// ---------------------------------------------------------------------------
__global__ __launch_bounds__(128) void feat_kernel(
    const float* __restrict__ pos, const float* __restrict__ charge,
    const float* __restrict__ elem, const float* __restrict__ namec,
    const float* __restrict__ Wf, const float* __restrict__ bf,
    float* __restrict__ q_out) {
    __shared__ float feats[16 * FEATD];  // 24832 B
    const int n0 = blockIdx.x * 16;
    const int tid = threadIdx.x;
    // element: offsets 4..131
    for (int i = tid; i < 16 * 128; i += 128)
        feats[(i >> 7) * FEATD + 4 + (i & 127)] = elem[(size_t)n0 * 128 + i];
    // name chars: offsets 132..387
    for (int i = tid; i < 16 * 256; i += 128)
        feats[(i >> 8) * FEATD + 132 + (i & 255)] = namec[(size_t)n0 * 256 + i];
    // pos: offsets 0..2 ; charge: offset 3
    if (tid < 48) feats[(tid / 3) * FEATD + (tid % 3)] = pos[n0 * 3 + tid];
    else if (tid < 64) feats[(tid - 48) * FEATD + 3] = charge[n0 + tid - 48];
    __syncthreads();

    const int d = tid;
    float acc[16];
#pragma unroll
    for (int a = 0; a < 16; ++a) acc[a] = 0.f;
    for (int f = 0; f < FEATD; ++f) {
        float wv = Wf[(size_t)f * 128 + d];
#pragma unroll
        for (int a = 0; a < 16; ++a) acc[a] += feats[a * FEATD + f] * wv;
    }
    const float bv = bf[d];
#pragma unroll
    for (int a = 0; a < 16; ++a)
        q_out[(size_t)(n0 + a) * 128 + d] = acc[a] + bv;
}

// ---------------------------------------------------------------------------
// Kernel 3: s2c = LN(s_trunk) @ W_s2c   [512, 384] -> [512, 128]
// block = 128 threads (2 waves), 8 tokens per block, grid 64
// ---------------------------------------------------------------------------
__global__ __launch_bounds__(128) void s2c_kernel(
    const float* __restrict__ s_trunk, const float* __restrict__ g,
    const float* __restrict__ bb, const float* __restrict__ W,
    float* __restrict__ s2c) {
    __shared__ float xln[8 * TOKEN_S];  // 12288 B
    const int wv = threadIdx.x >> 6, lane = threadIdx.x & 63;
    const int t0 = blockIdx.x * 8;
    for (int tt = wv; tt < 8; tt += 2) {
        const float* row = s_trunk + (size_t)(t0 + tt) * TOKEN_S;
        float vals[6];
        float s = 0.f, sq = 0.f;
#pragma unroll
        for (int m = 0; m < 6; ++m) {
            float v = row[lane + 64 * m];
            vals[m] = v; s += v; sq += v * v;
        }
#pragma unroll
        for (int off = 32; off >= 1; off >>= 1) {
            s += __shfl_xor(s, off, 64);
            sq += __shfl_xor(sq, off, 64);
        }
        float mean = s * (1.f / TOKEN_S);
        float var = sq * (1.f / TOKEN_S) - mean * mean;
        float rstd = rsqrtf(var + 1e-5f);
#pragma unroll
        for (int m = 0; m < 6; ++m) {
            int f = lane + 64 * m;
            xln[tt * TOKEN_S + f] = (vals[m] - mean) * rstd * g[f] + bb[f];
        }
    }
    __syncthreads();
    const int d = threadIdx.x;
    float acc[8];
#pragma unroll
    for (int tt = 0; tt < 8; ++tt) acc[tt] = 0.f;
    for (int f = 0; f < TOKEN_S; ++f) {
        float w = W[(size_t)f * ATOM_S + d];
#pragma unroll
        for (int tt = 0; tt < 8; ++tt) acc[tt] += xln[tt * TOKEN_S + f] * w;
    }
#pragma unroll
    for (int tt = 0; tt < 8; ++tt)
        s2c[(size_t)(t0 + tt) * ATOM_S + d] = acc[tt];
}

// ---------------------------------------------------------------------------
// Kernel 4: zp = LN(z) @ W_z2p   [512*512, 128] -> [512*512, 16]
// 8 lanes per row, 32 rows per 256-thread block, grid 8192
// W staged in LDS; column order swizzled by lane -> conflict-free broadcast
// ---------------------------------------------------------------------------
__global__ __launch_bounds__(256) void zp_kernel(
    const float* __restrict__ z, const float* __restrict__ g,
    const float* __restrict__ be, const float* __restrict__ Wz,
    float* __restrict__ zp) {
    __shared__ float Wl[TOKEN_Z * ATOM_Z];  // 8 KB
    for (int i = threadIdx.x; i < TOKEN_Z * ATOM_Z; i += 256) Wl[i] = Wz[i];
    __syncthreads();
    const int l = threadIdx.x & 7;
    const size_t row = (size_t)blockIdx.x * 32 + (threadIdx.x >> 3);
    const float* zr = z + row * TOKEN_Z + l * 16;
    float4 a0 = ((const float4*)zr)[0];
    float4 a1 = ((const float4*)zr)[1];
    float4 a2 = ((const float4*)zr)[2];
    float4 a3 = ((const float4*)zr)[3];
    float x[16] = {a0.x, a0.y, a0.z, a0.w, a1.x, a1.y, a1.z, a1.w,
                   a2.x, a2.y, a2.z, a2.w, a3.x, a3.y, a3.z, a3.w};
    float s = 0.f, sq = 0.f;
#pragma unroll
    for (int i = 0; i < 16; ++i) { s += x[i]; sq += x[i] * x[i]; }
#pragma unroll
    for (int m = 1; m <= 4; m <<= 1) {
        s += __shfl_xor(s, m, 8);
        sq += __shfl_xor(sq, m, 8);
    }
    const float mean = s * (1.f / TOKEN_Z);
    const float var = sq * (1.f / TOKEN_Z) - mean * mean;
    const float rstd = rsqrtf(var + 1e-5f);

    const float4* gp = (const float4*)(g + l * 16);
    const float4* bp = (const float4*)(be + l * 16);
    float4 g0 = gp[0], g1 = gp[1], g2 = gp[2], g3 = gp[3];
    float4 b0 = bp[0], b1 = bp[1], b2 = bp[2], b3 = bp[3];
    float gg[16] = {g0.x, g0.y, g0.z, g0.w, g1.x, g1.y, g1.z, g1.w,
                    g2.x, g2.y, g2.z, g2.w, g3.x, g3.y, g3.z, g3.w};
    float bbv[16] = {b0.x, b0.y, b0.z, b0.w, b1.x, b1.y, b1.z, b1.w,
                     b2.x, b2.y, b2.z, b2.w, b3.x, b3.y, b3.z, b3.w};
    float part[16];
#pragma unroll
    for (int i = 0; i < 16; ++i) part[i] = 0.f;
    const int fbase = l * 16;
#pragma unroll
    for (int i = 0; i < 16; ++i) {
        float xv = (x[i] - mean) * rstd * gg[i] + bbv[i];
        const float* wrow = Wl + (fbase + i) * 16;
#pragma unroll
        for (int jj = 0; jj < 16; ++jj) {
            int dcol = (jj + l) & 15;  // swizzle -> 8 distinct banks across lanes
            part[dcol] += xv * wrow[dcol];
        }
    }
#pragma unroll
    for (int m = 1; m <= 4; m <<= 1) {
#pragma unroll
        for (int dd = 0; dd < 16; ++dd)
            part[dd] += __shfl_xor(part[dd], m, 8);
    }
    float2 o;
    o.x = part[2 * l];
    o.y = part[2 * l + 1];
    *(float2*)(zp + row * 16 + 2 * l) = o;
}

// ---------------------------------------------------------------------------
// Kernel 5: c = c0 + s2c[tok]; a_cq = relu(c)@W_cq; a_ck = relu(c)@W_ck
// block = 128 threads, one atom per block
// ---------------------------------------------------------------------------
__global__ __launch_bounds__(128) void catk_kernel(
    const float* __restrict__ q_out, const float* __restrict__ s2c,
    const int* __restrict__ tok, const float* __restrict__ W_cq,
    const float* __restrict__ W_ck, float* __restrict__ c_out,
    float* __restrict__ a_cq, float* __restrict__ a_ck) {
    __shared__ float rc[128];
    const int n = blockIdx.x, d = threadIdx.x;
    const int t = tok[n];
    float cv = q_out[(size_t)n * 128 + d] + s2c[(size_t)t * 128 + d];
    c_out[(size_t)n * 128 + d] = cv;
    rc[d] = fmaxf(cv, 0.f);
    __syncthreads();
    if (d < 32) {
        const float* W = (d < 16) ? W_cq : W_ck;
        const int dd = d & 15;
        float acc = 0.f;
        for (int f = 0; f < 128; ++f) acc += rc[f] * W[f * 16 + dd];
        if (d < 16) a_cq[n * 16 + dd] = acc;
        else        a_ck[n * 16 + dd] = acc;
    }
}

// ---------------------------------------------------------------------------
// Kernel 6: pair tensor p [KWIN, 32, 128, 16]
// block = 128 threads (one per key slot kk), grid = KWIN*32 (one per (j,w))
// src atom for key kk of window j is 32j + kk - 48 (zero-padded out of range)
// ---------------------------------------------------------------------------
__global__ __launch_bounds__(128) void pair_kernel(
    const float* __restrict__ pos, const int* __restrict__ uid,
    const int* __restrict__ tok, const float* __restrict__ zp,
    const float* __restrict__ a_cq, const float* __restrict__ a_ck,
    const float* __restrict__ W_pos, const float* __restrict__ W_dist,
    const float* __restrict__ W_mask, const float* __restrict__ W_m1,
    const float* __restrict__ W_m2, const float* __restrict__ W_m3,
    float* __restrict__ p_out) {
    __shared__ float sWp[48], sWd[16], sWm[16];
    __shared__ float sW1[256], sW2[256], sW3[256];
    const int tid = threadIdx.x;
    for (int i = tid; i < 256; i += 128) {
        sW1[i] = W_m1[i]; sW2[i] = W_m2[i]; sW3[i] = W_m3[i];
    }
    if (tid < 48) sWp[tid] = W_pos[tid];
    if (tid >= 64 && tid < 80) sWd[tid - 64] = W_dist[tid - 64];
    if (tid >= 96 && tid < 112) sWm[tid - 96] = W_mask[tid - 96];
    __syncthreads();

    const int j = blockIdx.x >> 5, w = blockIdx.x & 31;
    const int qatom = j * 32 + w;
    const float pqx = pos[qatom * 3 + 0];
    const float pqy = pos[qatom * 3 + 1];
    const float pqz = pos[qatom * 3 + 2];
    const int uq = uid[qatom];
    const int tq = tok[qatom];
    const float4* acq4 = (const float4*)(a_cq + (size_t)qatom * 16);
    float4 q0 = acq4[0], q1 = acq4[1], q2 = acq4[2], q3 = acq4[3];
    float acqv[16] = {q0.x, q0.y, q0.z, q0.w, q1.x, q1.y, q1.z, q1.w,
                      q2.x, q2.y, q2.z, q2.w, q3.x, q3.y, q3.z, q3.w};

    const int kk = tid;
    const int src = j * 32 + kk - 48;
    const bool valid = ((unsigned)src < (unsigned)N_ATOMS);
    float vflag = 0.f, dx = 0.f, dy = 0.f, dz = 0.f, dn = 0.f;
    float add[16];
#pragma unroll
    for (int i = 0; i < 16; ++i) add[i] = 0.f;
    if (valid) {
        dx = pos[src * 3 + 0] - pqx;
        dy = pos[src * 3 + 1] - pqy;
        dz = pos[src * 3 + 2] - pqz;
        dn = 1.f / (1.f + dx * dx + dy * dy + dz * dz);
        vflag = (uid[src] == uq) ? 1.f : 0.f;
        const int tk_ = tok[src];
        const float4* zr4 = (const float4*)(zp + ((size_t)tq * 512 + tk_) * 16);
        const float4* ar4 = (const float4*)(a_ck + (size_t)src * 16);
        float4 z0 = zr4[0], z1 = zr4[1], z2 = zr4[2], z3 = zr4[3];
        float4 c0 = ar4[0], c1 = ar4[1], c2 = ar4[2], c3 = ar4[3];
        add[0] = z0.x + c0.x; add[1] = z0.y + c0.y; add[2] = z0.z + c0.z; add[3] = z0.w + c0.w;
        add[4] = z1.x + c1.x; add[5] = z1.y + c1.y; add[6] = z1.z + c1.z; add[7] = z1.w + c1.w;
        add[8] = z2.x + c2.x; add[9] = z2.y + c2.y; add[10] = z2.z + c2.z; add[11] = z2.w + c2.w;
        add[12] = z3.x + c3.x; add[13] = z3.y + c3.y; add[14] = z3.z + c3.z; add[15] = z3.w + c3.w;
    }
    float pb[16], rp[16];
#pragma unroll
    for (int d = 0; d < 16; ++d) {
        float t = dx * sWp[d] + dy * sWp[16 + d] + dz * sWp[32 + d] +
                  dn * sWd[d] + sWm[d];
        pb[d] = vflag * t + add[d] + acqv[d];
        rp[d] = fmaxf(pb[d], 0.f);
    }
    float t1[16];
#pragma unroll
    for (int d = 0; d < 16; ++d) {
        float s = 0.f;
#pragma unroll
        for (int f = 0; f < 16; ++f) s += rp[f] * sW1[f * 16 + d];
        t1[d] = fmaxf(s, 0.f);
    }
    float t2[16];
#pragma unroll
    for (int d = 0; d < 16; ++d) {
        float s = 0.f;
#pragma unroll
        for (int f = 0; f < 16; ++f) s += t1[f] * sW2[f * 16 + d];
        t2[d] = fmaxf(s, 0.f);
    }
    float o[16];
#pragma unroll
    for (int d = 0; d < 16; ++d) {
        float s = 0.f;
#pragma unroll
        for (int f = 0; f < 16; ++f) s += t2[f] * sW3[f * 16 + d];
        o[d] = pb[d] + s;
    }
    float* op = p_out + ((size_t)blockIdx.x * 128 + kk) * 16;
    ((float4*)op)[0] = make_float4(o[0], o[1], o[2], o[3]);
    ((float4*)op)[1] = make_float4(o[4], o[5], o[6], o[7]);
    ((float4*)op)[2] = make_float4(o[8], o[9], o[10], o[11]);
    ((float4*)op)[3] = make_float4(o[12], o[13], o[14], o[15]);
}

// ---------------------------------------------------------------------------
extern "C" void kernel_launch(void* const* d_in, const int* in_sizes, int n_in,
                              void* d_out, int out_size, void* d_ws, size_t ws_size,
                              hipStream_t stream) {
    const float* ref_pos     = (const float*)d_in[0];
    const float* ref_charge  = (const float*)d_in[1];
    const float* ref_element = (const float*)d_in[2];
    const float* ref_name    = (const float*)d_in[3];
    // d_in[4] atom_pad_mask: all-True in this problem; mk reduces to src-validity
    const int*   uid         = (const int*)d_in[5];
    const float* a2t         = (const float*)d_in[6];
    const float* s_trunk     = (const float*)d_in[7];
    const float* z           = (const float*)d_in[8];
    const float* W_feat      = (const float*)d_in[9];
    const float* b_feat      = (const float*)d_in[10];
    const float* W_pos       = (const float*)d_in[11];
    const float* W_dist      = (const float*)d_in[12];
    const float* W_mask      = (const float*)d_in[13];
    const float* ln_s_g      = (const float*)d_in[14];
    const float* ln_s_b      = (const float*)d_in[15];
    const float* W_s2c       = (const float*)d_in[16];
    const float* ln_z_g      = (const float*)d_in[17];
    const float* ln_z_b      = (const float*)d_in[18];
    const float* W_z2p       = (const float*)d_in[19];
    const float* W_cq        = (const float*)d_in[20];
    const float* W_ck        = (const float*)d_in[21];
    const float* W_m1        = (const float*)d_in[22];
    const float* W_m2        = (const float*)d_in[23];
    const float* W_m3        = (const float*)d_in[24];

    float* out = (float*)d_out;
    float* q_out = out;                        // 4096*128
    float* c_out = out + 524288;               // 4096*128
    float* p_out = out + 1048576;              // 128*32*128*16

    float* zp  = (float*)d_ws;                 // 512*512*16 = 4194304 floats
    float* s2c = zp + 4194304;                 // 512*128
    float* acq = s2c + 65536;                  // 4096*16
    float* ack = acq + 65536;                  // 4096*16
    int*   tok = (int*)(ack + 65536);          // 4096

    tok_kernel<<<1024, 256, 0, stream>>>(a2t, tok);
    feat_kernel<<<256, 128, 0, stream>>>(ref_pos, ref_charge, ref_element,
                                         ref_name, W_feat, b_feat, q_out);
    s2c_kernel<<<64, 128, 0, stream>>>(s_trunk, ln_s_g, ln_s_b, W_s2c, s2c);
    zp_kernel<<<8192, 256, 0, stream>>>(z, ln_z_g, ln_z_b, W_z2p, zp);
    catk_kernel<<<4096, 128, 0, stream>>>(q_out, s2c, tok, W_cq, W_ck,
                                          c_out, acq, ack);
    pair_kernel<<<4096, 128, 0, stream>>>(ref_pos, uid, tok, zp, acq, ack,
                                          W_pos, W_dist, W_mask,
                                          W_m1, W_m2, W_m3, p_out);
}

// Round 2
// 405.800 us; speedup vs baseline: 2.9933x; 2.9933x over previous
//
#include <hip/hip_runtime.h>
#include <hip/hip_bf16.h>

#define N_ATOMS 4096
#define T_TOK   512
#define ATOM_S  128
#define ATOM_Z  16
#define TOKEN_S 384
#define TOKEN_Z 128
#define FEATD   388

using bfrag = __attribute__((ext_vector_type(8))) short;   // 8 bf16 in 4 VGPRs
using f4    = __attribute__((ext_vector_type(4))) float;

__device__ __forceinline__ short f2bf(float f) {
    unsigned u = __float_as_uint(f);
    unsigned r = u + 0x7FFFu + ((u >> 16) & 1u);   // round-nearest-even
    return (short)(r >> 16);
}

// ---------------------------------------------------------------------------
// Kernel 1: extract token index per atom from one-hot atom_to_token [N, T]
// ---------------------------------------------------------------------------
__global__ __launch_bounds__(256) void tok_kernel(const float* __restrict__ a2t,
                                                  int* __restrict__ tok) {
    const int wave = threadIdx.x >> 6;
    const int lane = threadIdx.x & 63;
    const int n = blockIdx.x * 4 + wave;
    if (n >= N_ATOMS) return;
    const float* row = a2t + (size_t)n * T_TOK;
    int found = 0;
#pragma unroll
    for (int m = 0; m < T_TOK / 64; ++m) {
        float v = row[lane + 64 * m];
        if (v > 0.5f) found = lane + 64 * m;
    }
#pragma unroll
    for (int off = 32; off >= 1; off >>= 1)
        found = max(found, __shfl_xor(found, off, 64));
    if (lane == 0) tok[n] = found;
}

// ---------------------------------------------------------------------------
// Kernel 2: c0 = atom_feats @ W_feat + b_feat  -> q output [N, 128]
// block = 128 threads (one output dim each), 8 atoms per block, grid 512
// ---------------------------------------------------------------------------
__global__ __launch_bounds__(128) void feat_kernel(
    const float* __restrict__ pos, const float* __restrict__ charge,
    const float* __restrict__ elem, const float* __restrict__ namec,
    const float* __restrict__ Wf, const float* __restrict__ bf,
    float* __restrict__ q_out) {
    __shared__ float feats[8 * FEATD];  // 12416 B, rows 16B-aligned (388*4=1552)
    const int n0 = blockIdx.x * 8;
    const int tid = threadIdx.x;
    // element: offsets 4..131
    for (int i = tid; i < 8 * 128; i += 128)
        feats[(i >> 7) * FEATD + 4 + (i & 127)] = elem[(size_t)n0 * 128 + i];
    // name chars: offsets 132..387
    for (int i = tid; i < 8 * 256; i += 128)
        feats[(i >> 8) * FEATD + 132 + (i & 255)] = namec[(size_t)n0 * 256 + i];
    // pos 0..2, charge 3
    if (tid < 24) feats[(tid / 3) * FEATD + (tid % 3)] = pos[n0 * 3 + tid];
    else if (tid < 32) feats[(tid - 24) * FEATD + 3] = charge[n0 + tid - 24];
    __syncthreads();

    const int d = tid;
    float acc[8];
#pragma unroll
    for (int a = 0; a < 8; ++a) acc[a] = 0.f;
    for (int f = 0; f < FEATD; f += 4) {
        const float w0 = Wf[(size_t)(f + 0) * 128 + d];
        const float w1 = Wf[(size_t)(f + 1) * 128 + d];
        const float w2 = Wf[(size_t)(f + 2) * 128 + d];
        const float w3 = Wf[(size_t)(f + 3) * 128 + d];
#pragma unroll
        for (int a = 0; a < 8; ++a) {
            float4 fv = *(const float4*)&feats[a * FEATD + f];  // broadcast b128
            acc[a] = fmaf(fv.x, w0, acc[a]);
            acc[a] = fmaf(fv.y, w1, acc[a]);
            acc[a] = fmaf(fv.z, w2, acc[a]);
            acc[a] = fmaf(fv.w, w3, acc[a]);
        }
    }
    const float bv = bf[d];
#pragma unroll
    for (int a = 0; a < 8; ++a)
        q_out[(size_t)(n0 + a) * 128 + d] = acc[a] + bv;
}

// ---------------------------------------------------------------------------
// Kernel 3: s2c = LN(s_trunk) @ W_s2c   [512, 384] -> [512, 128]
// ---------------------------------------------------------------------------
__global__ __launch_bounds__(128) void s2c_kernel(
    const float* __restrict__ s_trunk, const float* __restrict__ g,
    const float* __restrict__ bb, const float* __restrict__ W,
    float* __restrict__ s2c) {
    __shared__ float xln[8 * TOKEN_S];
    const int wv = threadIdx.x >> 6, lane = threadIdx.x & 63;
    const int t0 = blockIdx.x * 8;
    for (int tt = wv; tt < 8; tt += 2) {
        const float* row = s_trunk + (size_t)(t0 + tt) * TOKEN_S;
        float vals[6];
        float s = 0.f, sq = 0.f;
#pragma unroll
        for (int m = 0; m < 6; ++m) {
            float v = row[lane + 64 * m];
            vals[m] = v; s += v; sq += v * v;
        }
#pragma unroll
        for (int off = 32; off >= 1; off >>= 1) {
            s += __shfl_xor(s, off, 64);
            sq += __shfl_xor(sq, off, 64);
        }
        float mean = s * (1.f / TOKEN_S);
        float var = sq * (1.f / TOKEN_S) - mean * mean;
        float rstd = rsqrtf(var + 1e-5f);
#pragma unroll
        for (int m = 0; m < 6; ++m) {
            int f = lane + 64 * m;
            xln[tt * TOKEN_S + f] = (vals[m] - mean) * rstd * g[f] + bb[f];
        }
    }
    __syncthreads();
    const int d = threadIdx.x;
    float acc[8];
#pragma unroll
    for (int tt = 0; tt < 8; ++tt) acc[tt] = 0.f;
    for (int f = 0; f < TOKEN_S; ++f) {
        float w = W[(size_t)f * ATOM_S + d];
#pragma unroll
        for (int tt = 0; tt < 8; ++tt) acc[tt] += xln[tt * TOKEN_S + f] * w;
    }
#pragma unroll
    for (int tt = 0; tt < 8; ++tt)
        s2c[(size_t)(t0 + tt) * ATOM_S + d] = acc[tt];
}

// ---------------------------------------------------------------------------
// Kernel 4a: prep for zp GEMM.
//   wfrag[kb][lane][j] = bf16( g[k] * Wz[k][n] ),  k = (lane>>4)*8+j+32*kb,
//   n = lane&15  (exact B-fragment order for mfma_f32_16x16x32_bf16)
//   bias16[n] = sum_k b[k] * Wz[k][n]
// ---------------------------------------------------------------------------
__global__ __launch_bounds__(256) void zprep_kernel(
    const float* __restrict__ Wz, const float* __restrict__ g,
    const float* __restrict__ be, short* __restrict__ wfrag,
    float* __restrict__ bias16) {
    const int t = threadIdx.x;
    const int lane = t & 63, kb = t >> 6;
    const int quad = lane >> 4, n = lane & 15;
    short v[8];
#pragma unroll
    for (int j = 0; j < 8; ++j) {
        int k = quad * 8 + j + 32 * kb;
        v[j] = f2bf(g[k] * Wz[k * 16 + n]);
    }
    short* dst = wfrag + (size_t)(kb * 64 + lane) * 8;
#pragma unroll
    for (int j = 0; j < 8; ++j) dst[j] = v[j];
    if (t < 16) {
        float s = 0.f;
        for (int k = 0; k < 128; ++k) s += be[k] * Wz[k * 16 + t];
        bias16[t] = s;
    }
}

// ---------------------------------------------------------------------------
// Kernel 4b: zp = LN(z) @ W' + bias   [262144, 128] -> [262144, 16]  via MFMA
// one wave per 16-row tile; 4 waves/block; grid 4096
// ---------------------------------------------------------------------------
__global__ __launch_bounds__(256) void zp_mfma_kernel(
    const float* __restrict__ z, const short* __restrict__ wfrag,
    const float* __restrict__ bias16, float* __restrict__ zp) {
    const int wave = threadIdx.x >> 6, lane = threadIdx.x & 63;
    const size_t tile = (size_t)blockIdx.x * 4 + wave;
    const size_t r0 = tile * 16;
    const int m = lane & 15, quad = lane >> 4;

    const float* zrow = z + (r0 + m) * (size_t)TOKEN_Z;
    float x[32];
#pragma unroll
    for (int kb = 0; kb < 4; ++kb) {
        const float4* p = (const float4*)(zrow + quad * 8 + 32 * kb);
        float4 a = p[0], b2 = p[1];
        x[kb * 8 + 0] = a.x;  x[kb * 8 + 1] = a.y;
        x[kb * 8 + 2] = a.z;  x[kb * 8 + 3] = a.w;
        x[kb * 8 + 4] = b2.x; x[kb * 8 + 5] = b2.y;
        x[kb * 8 + 6] = b2.z; x[kb * 8 + 7] = b2.w;
    }
    float s = 0.f, sq = 0.f;
#pragma unroll
    for (int i = 0; i < 32; ++i) { s += x[i]; sq = fmaf(x[i], x[i], sq); }
    s  += __shfl_xor(s, 16, 64);  s  += __shfl_xor(s, 32, 64);
    sq += __shfl_xor(sq, 16, 64); sq += __shfl_xor(sq, 32, 64);
    const float mean = s * (1.f / TOKEN_Z);
    const float var  = sq * (1.f / TOKEN_Z) - mean * mean;
    const float rstd = rsqrtf(var + 1e-5f);

    const bfrag* wb = (const bfrag*)wfrag;
    const float bias = bias16[m];
    f4 acc = {bias, bias, bias, bias};
#pragma unroll
    for (int kb = 0; kb < 4; ++kb) {
        bfrag af;
#pragma unroll
        for (int j = 0; j < 8; ++j)
            af[j] = f2bf((x[kb * 8 + j] - mean) * rstd);
        acc = __builtin_amdgcn_mfma_f32_16x16x32_bf16(af, wb[kb * 64 + lane],
                                                      acc, 0, 0, 0);
    }
    float* orow = zp + r0 * 16;
#pragma unroll
    for (int reg = 0; reg < 4; ++reg)
        orow[(quad * 4 + reg) * 16 + m] = acc[reg];
}

// ---------------------------------------------------------------------------
// Kernel 5: c = c0 + s2c[tok]; a_cq = relu(c)@W_cq; a_ck = relu(c)@W_ck
// ---------------------------------------------------------------------------
__global__ __launch_bounds__(128) void catk_kernel(
    const float* __restrict__ q_out, const float* __restrict__ s2c,
    const int* __restrict__ tok, const float* __restrict__ W_cq,
    const float* __restrict__ W_ck, float* __restrict__ c_out,
    float* __restrict__ a_cq, float* __restrict__ a_ck) {
    __shared__ float rc[128];
    const int n = blockIdx.x, d = threadIdx.x;
    const int t = tok[n];
    float cv = q_out[(size_t)n * 128 + d] + s2c[(size_t)t * 128 + d];
    c_out[(size_t)n * 128 + d] = cv;
    rc[d] = fmaxf(cv, 0.f);
    __syncthreads();
    if (d < 32) {
        const float* W = (d < 16) ? W_cq : W_ck;
        const int dd = d & 15;
        float acc = 0.f;
        for (int f = 0; f < 128; ++f) acc += rc[f] * W[f * 16 + dd];
        if (d < 16) a_cq[n * 16 + dd] = acc;
        else        a_ck[n * 16 + dd] = acc;
    }
}

// ---------------------------------------------------------------------------
// Kernel 6: pair tensor p [KWIN, 32, 128, 16]
// ---------------------------------------------------------------------------
__global__ __launch_bounds__(128) void pair_kernel(
    const float* __restrict__ pos, const int* __restrict__ uid,
    const int* __restrict__ tok, const float* __restrict__ zp,
    const float* __restrict__ a_cq, const float* __restrict__ a_ck,
    const float* __restrict__ W_pos, const float* __restrict__ W_dist,
    const float* __restrict__ W_mask, const float* __restrict__ W_m1,
    const float* __restrict__ W_m2, const float* __restrict__ W_m3,
    float* __restrict__ p_out) {
    __shared__ float sWp[48], sWd[16], sWm[16];
    __shared__ float sW1[256], sW2[256], sW3[256];
    const int tid = threadIdx.x;
    for (int i = tid; i < 256; i += 128) {
        sW1[i] = W_m1[i]; sW2[i] = W_m2[i]; sW3[i] = W_m3[i];
    }
    if (tid < 48) sWp[tid] = W_pos[tid];
    if (tid >= 64 && tid < 80) sWd[tid - 64] = W_dist[tid - 64];
    if (tid >= 96 && tid < 112) sWm[tid - 96] = W_mask[tid - 96];
    __syncthreads();

    const int j = blockIdx.x >> 5, w = blockIdx.x & 31;
    const int qatom = j * 32 + w;
    const float pqx = pos[qatom * 3 + 0];
    const float pqy = pos[qatom * 3 + 1];
    const float pqz = pos[qatom * 3 + 2];
    const int uq = uid[qatom];
    const int tq = tok[qatom];
    const float4* acq4 = (const float4*)(a_cq + (size_t)qatom * 16);
    float4 q0 = acq4[0], q1 = acq4[1], q2 = acq4[2], q3 = acq4[3];
    float acqv[16] = {q0.x, q0.y, q0.z, q0.w, q1.x, q1.y, q1.z, q1.w,
                      q2.x, q2.y, q2.z, q2.w, q3.x, q3.y, q3.z, q3.w};

    const int kk = tid;
    const int src = j * 32 + kk - 48;
    const bool valid = ((unsigned)src < (unsigned)N_ATOMS);
    float vflag = 0.f, dx = 0.f, dy = 0.f, dz = 0.f, dn = 0.f;
    float add[16];
#pragma unroll
    for (int i = 0; i < 16; ++i) add[i] = 0.f;
    if (valid) {
        dx = pos[src * 3 + 0] - pqx;
        dy = pos[src * 3 + 1] - pqy;
        dz = pos[src * 3 + 2] - pqz;
        dn = 1.f / (1.f + dx * dx + dy * dy + dz * dz);
        vflag = (uid[src] == uq) ? 1.f : 0.f;
        const int tk_ = tok[src];
        const float4* zr4 = (const float4*)(zp + ((size_t)tq * 512 + tk_) * 16);
        const float4* ar4 = (const float4*)(a_ck + (size_t)src * 16);
        float4 z0 = zr4[0], z1 = zr4[1], z2 = zr4[2], z3 = zr4[3];
        float4 c0 = ar4[0], c1 = ar4[1], c2 = ar4[2], c3 = ar4[3];
        add[0] = z0.x + c0.x; add[1] = z0.y + c0.y; add[2] = z0.z + c0.z; add[3] = z0.w + c0.w;
        add[4] = z1.x + c1.x; add[5] = z1.y + c1.y; add[6] = z1.z + c1.z; add[7] = z1.w + c1.w;
        add[8] = z2.x + c2.x; add[9] = z2.y + c2.y; add[10] = z2.z + c2.z; add[11] = z2.w + c2.w;
        add[12] = z3.x + c3.x; add[13] = z3.y + c3.y; add[14] = z3.z + c3.z; add[15] = z3.w + c3.w;
    }
    float pb[16], rp[16];
#pragma unroll
    for (int d = 0; d < 16; ++d) {
        float t = dx * sWp[d] + dy * sWp[16 + d] + dz * sWp[32 + d] +
                  dn * sWd[d] + sWm[d];
        pb[d] = vflag * t + add[d] + acqv[d];
        rp[d] = fmaxf(pb[d], 0.f);
    }
    float t1[16];
#pragma unroll
    for (int d = 0; d < 16; ++d) {
        float s = 0.f;
#pragma unroll
        for (int f = 0; f < 16; ++f) s += rp[f] * sW1[f * 16 + d];
        t1[d] = fmaxf(s, 0.f);
    }
    float t2[16];
#pragma unroll
    for (int d = 0; d < 16; ++d) {
        float s = 0.f;
#pragma unroll
        for (int f = 0; f < 16; ++f) s += t1[f] * sW2[f * 16 + d];
        t2[d] = fmaxf(s, 0.f);
    }
    float o[16];
#pragma unroll
    for (int d = 0; d < 16; ++d) {
        float s = 0.f;
#pragma unroll
        for (int f = 0; f < 16; ++f) s += t2[f] * sW3[f * 16 + d];
        o[d] = pb[d] + s;
    }
    float* op = p_out + ((size_t)blockIdx.x * 128 + kk) * 16;
    ((float4*)op)[0] = make_float4(o[0], o[1], o[2], o[3]);
    ((float4*)op)[1] = make_float4(o[4], o[5], o[6], o[7]);
    ((float4*)op)[2] = make_float4(o[8], o[9], o[10], o[11]);
    ((float4*)op)[3] = make_float4(o[12], o[13], o[14], o[15]);
}

// ---------------------------------------------------------------------------
extern "C" void kernel_launch(void* const* d_in, const int* in_sizes, int n_in,
                              void* d_out, int out_size, void* d_ws, size_t ws_size,
                              hipStream_t stream) {
    const float* ref_pos     = (const float*)d_in[0];
    const float* ref_charge  = (const float*)d_in[1];
    const float* ref_element = (const float*)d_in[2];
    const float* ref_name    = (const float*)d_in[3];
    const int*   uid         = (const int*)d_in[5];
    const float* a2t         = (const float*)d_in[6];
    const float* s_trunk     = (const float*)d_in[7];
    const float* z           = (const float*)d_in[8];
    const float* W_feat      = (const float*)d_in[9];
    const float* b_feat      = (const float*)d_in[10];
    const float* W_pos       = (const float*)d_in[11];
    const float* W_dist      = (const float*)d_in[12];
    const float* W_mask      = (const float*)d_in[13];
    const float* ln_s_g      = (const float*)d_in[14];
    const float* ln_s_b      = (const float*)d_in[15];
    const float* W_s2c       = (const float*)d_in[16];
    const float* ln_z_g      = (const float*)d_in[17];
    const float* ln_z_b      = (const float*)d_in[18];
    const float* W_z2p       = (const float*)d_in[19];
    const float* W_cq        = (const float*)d_in[20];
    const float* W_ck        = (const float*)d_in[21];
    const float* W_m1        = (const float*)d_in[22];
    const float* W_m2        = (const float*)d_in[23];
    const float* W_m3        = (const float*)d_in[24];

    float* out = (float*)d_out;
    float* q_out = out;                        // 4096*128
    float* c_out = out + 524288;               // 4096*128
    float* p_out = out + 1048576;              // 128*32*128*16

    float* zp   = (float*)d_ws;                // 512*512*16 floats
    float* s2c  = zp + 4194304;                // 512*128
    float* acq  = s2c + 65536;                 // 4096*16
    float* ack  = acq + 65536;                 // 4096*16
    int*   tok  = (int*)(ack + 65536);         // 4096 ints
    short* wfrag = (short*)(tok + 4096);       // 4*64*8 bf16
    float* bias16 = (float*)(wfrag + 2048);    // 16 floats

    tok_kernel<<<1024, 256, 0, stream>>>(a2t, tok);
    zprep_kernel<<<1, 256, 0, stream>>>(W_z2p, ln_z_g, ln_z_b, wfrag, bias16);
    feat_kernel<<<512, 128, 0, stream>>>(ref_pos, ref_charge, ref_element,
                                         ref_name, W_feat, b_feat, q_out);
    s2c_kernel<<<64, 128, 0, stream>>>(s_trunk, ln_s_g, ln_s_b, W_s2c, s2c);
    zp_mfma_kernel<<<4096, 256, 0, stream>>>(z, wfrag, bias16, zp);
    catk_kernel<<<4096, 128, 0, stream>>>(q_out, s2c, tok, W_cq, W_ck,
                                          c_out, acq, ack);
    pair_kernel<<<4096, 128, 0, stream>>>(ref_pos, uid, tok, zp, acq, ack,
                                          W_pos, W_dist, W_mask,
                                          W_m1, W_m2, W_m3, p_out);
}

// Round 3
// 327.391 us; speedup vs baseline: 3.7102x; 1.2395x over previous
//
#include <hip/hip_runtime.h>

#define N_ATOMS 4096
#define T_TOK   512
#define TOKEN_S 384
#define TOKEN_Z 128

using bfrag = __attribute__((ext_vector_type(8))) short;   // 8 bf16 (4 VGPRs)
using f4    = __attribute__((ext_vector_type(4))) float;

__device__ __forceinline__ short f2bf(float f) {
    unsigned u = __float_as_uint(f);
    unsigned r = u + 0x7FFFu + ((u >> 16) & 1u);   // RNE
    return (short)(r >> 16);
}
__device__ __forceinline__ float bf2f(short s) {
    return __uint_as_float(((unsigned)(unsigned short)s) << 16);
}

// ---------------------------------------------------------------------------
// Kernel 1: token index per atom from one-hot [N, T]
// ---------------------------------------------------------------------------
__global__ __launch_bounds__(256) void tok_kernel(const float* __restrict__ a2t,
                                                  int* __restrict__ tok) {
    const int wave = threadIdx.x >> 6, lane = threadIdx.x & 63;
    const int n = blockIdx.x * 4 + wave;
    if (n >= N_ATOMS) return;
    const float* row = a2t + (size_t)n * T_TOK;
    int found = 0;
#pragma unroll
    for (int m = 0; m < T_TOK / 64; ++m)
        if (row[lane + 64 * m] > 0.5f) found = lane + 64 * m;
#pragma unroll
    for (int off = 32; off >= 1; off >>= 1)
        found = max(found, __shfl_xor(found, off, 64));
    if (lane == 0) tok[n] = found;
}

// ---------------------------------------------------------------------------
// Kernel 2: prep — build all bf16 weight fragments (B-frag order:
//   lane holds B[k][n], k=quad*8+j, n=lane&15) + zp bias/colsum vectors.
// frag sets: 0..3   zpW   (k over 128, n=16)   from g*W_z2p
//            4..99  featW (12 kb x 8 ntiles)   from W_feat rows 4..387
//            100..103 WcqF, 104..107 WckF      (k over 128, n=16)
// block 27 (last): bias16[n]=sum_k b[k]Wz[k][n]; cs16[n]=sum_k g[k]Wz[k][n]
// ---------------------------------------------------------------------------
__global__ __launch_bounds__(256) void prep_kernel(
    const float* __restrict__ Wz, const float* __restrict__ gz,
    const float* __restrict__ bz, const float* __restrict__ Wf,
    const float* __restrict__ Wcq, const float* __restrict__ Wck,
    short* __restrict__ zpW, short* __restrict__ featW,
    short* __restrict__ WcqF, short* __restrict__ WckF,
    float* __restrict__ bias16, float* __restrict__ cs16) {
    if (blockIdx.x == 27) {
        const int t = threadIdx.x;
        if (t < 16) {
            float s = 0.f;
            for (int k = 0; k < 128; ++k) s += bz[k] * Wz[k * 16 + t];
            bias16[t] = s;
        } else if (t < 32) {
            const int n = t - 16;
            float s = 0.f;
            for (int k = 0; k < 128; ++k) s += gz[k] * Wz[k * 16 + n];
            cs16[n] = s;
        }
        return;
    }
    const int id = blockIdx.x * 256 + threadIdx.x;
    const int lane = id & 63, fs = id >> 6;
    const int quad = lane >> 4, n = lane & 15;
    short v[8];
    short* dst;
    if (fs < 4) {                       // zp weights: W' = g*Wz
#pragma unroll
        for (int j = 0; j < 8; ++j) {
            int k = fs * 32 + quad * 8 + j;
            v[j] = f2bf(gz[k] * Wz[k * 16 + n]);
        }
        dst = zpW + (size_t)(fs * 64 + lane) * 8;
    } else if (fs < 100) {              // feat weights rows 4..387
        const int idx = fs - 4, kb = idx >> 3, nt = idx & 7;
#pragma unroll
        for (int j = 0; j < 8; ++j) {
            int f = 4 + kb * 32 + quad * 8 + j;
            v[j] = f2bf(Wf[(size_t)f * 128 + nt * 16 + n]);
        }
        dst = featW + (size_t)(idx * 64 + lane) * 8;
    } else if (fs < 104) {              // W_cq frags
        const int kb = fs - 100;
#pragma unroll
        for (int j = 0; j < 8; ++j) {
            int k = kb * 32 + quad * 8 + j;
            v[j] = f2bf(Wcq[k * 16 + n]);
        }
        dst = WcqF + (size_t)(kb * 64 + lane) * 8;
    } else {                            // W_ck frags
        const int kb = fs - 104;
#pragma unroll
        for (int j = 0; j < 8; ++j) {
            int k = kb * 32 + quad * 8 + j;
            v[j] = f2bf(Wck[k * 16 + n]);
        }
        dst = WckF + (size_t)(kb * 64 + lane) * 8;
    }
#pragma unroll
    for (int j = 0; j < 8; ++j) dst[j] = v[j];
}

// ---------------------------------------------------------------------------
// Kernel 3: s2c = LN(s_trunk) @ W_s2c   [512,384] -> [512,128]
// ---------------------------------------------------------------------------
__global__ __launch_bounds__(128) void s2c_kernel(
    const float* __restrict__ s_trunk, const float* __restrict__ g,
    const float* __restrict__ bb, const float* __restrict__ W,
    float* __restrict__ s2c) {
    __shared__ float xln[8 * TOKEN_S];
    const int wv = threadIdx.x >> 6, lane = threadIdx.x & 63;
    const int t0 = blockIdx.x * 8;
    for (int tt = wv; tt < 8; tt += 2) {
        const float* row = s_trunk + (size_t)(t0 + tt) * TOKEN_S;
        float vals[6];
        float s = 0.f, sq = 0.f;
#pragma unroll
        for (int m = 0; m < 6; ++m) {
            float v = row[lane + 64 * m];
            vals[m] = v; s += v; sq += v * v;
        }
#pragma unroll
        for (int off = 32; off >= 1; off >>= 1) {
            s += __shfl_xor(s, off, 64);
            sq += __shfl_xor(sq, off, 64);
        }
        float mean = s * (1.f / TOKEN_S);
        float var = sq * (1.f / TOKEN_S) - mean * mean;
        float rstd = rsqrtf(var + 1e-5f);
#pragma unroll
        for (int m = 0; m < 6; ++m) {
            int f = lane + 64 * m;
            xln[tt * TOKEN_S + f] = (vals[m] - mean) * rstd * g[f] + bb[f];
        }
    }
    __syncthreads();
    const int d = threadIdx.x;
    float acc[8];
#pragma unroll
    for (int tt = 0; tt < 8; ++tt) acc[tt] = 0.f;
    for (int f = 0; f < TOKEN_S; ++f) {
        float w = W[(size_t)f * 128 + d];
#pragma unroll
        for (int tt = 0; tt < 8; ++tt) acc[tt] += xln[tt * TOKEN_S + f] * w;
    }
#pragma unroll
    for (int tt = 0; tt < 8; ++tt)
        s2c[(size_t)(t0 + tt) * 128 + d] = acc[tt];
}

// ---------------------------------------------------------------------------
// Kernel 4: zp = LN(z) @ W' + bias  via raw-bf16 MFMA + affine epilogue:
//   zp[r,n] = rstd_r*(x@W')[r,n] - rstd_r*mu_r*cs[n] + bias[n]
// Coalesced f32 load -> bf16 -> LDS (272B padded rows) -> frag ds_read_b128.
// ---------------------------------------------------------------------------
__global__ __launch_bounds__(256) void zp_mfma_kernel(
    const float* __restrict__ z, const short* __restrict__ zpW,
    const float* __restrict__ bias16, const float* __restrict__ cs16,
    float* __restrict__ zp) {
    __shared__ short zt[4][16 * 136];   // per-wave [16][136] bf16, 272 B rows
    const int wave = threadIdx.x >> 6, lane = threadIdx.x & 63;
    const int m = lane & 15, quad = lane >> 4;
    const size_t tile = (size_t)blockIdx.x * 4 + wave;
    const size_t r0 = tile * 16;
    const float* zb = z + r0 * 128;
    short* tw = &zt[wave][0];
    // stage: 8 coalesced 1KB loads, pack to bf16, ds_write 8B
#pragma unroll
    for (int i = 0; i < 8; ++i) {
        const int flat = i * 256 + lane * 4;
        float4 v = *(const float4*)(zb + flat);
        const int r = flat >> 7, c = flat & 127;
        int2 pk;
        pk.x = ((unsigned)(unsigned short)f2bf(v.y) << 16) |
               (unsigned)(unsigned short)f2bf(v.x);
        pk.y = ((unsigned)(unsigned short)f2bf(v.w) << 16) |
               (unsigned)(unsigned short)f2bf(v.z);
        *(int2*)&tw[r * 136 + c] = pk;
    }
    __syncthreads();
    // frag reads + stats from bf16 values
    bfrag A[4];
    float xs = 0.f, xq = 0.f;
#pragma unroll
    for (int kb = 0; kb < 4; ++kb) {
        A[kb] = *(const bfrag*)&tw[m * 136 + kb * 32 + quad * 8];
#pragma unroll
        for (int j = 0; j < 8; ++j) {
            float xv = bf2f(A[kb][j]);
            xs += xv; xq = fmaf(xv, xv, xq);
        }
    }
    xs += __shfl_xor(xs, 16, 64); xs += __shfl_xor(xs, 32, 64);
    xq += __shfl_xor(xq, 16, 64); xq += __shfl_xor(xq, 32, 64);
    const float mean = xs * (1.f / 128.f);
    const float var  = xq * (1.f / 128.f) - mean * mean;
    const float rstd = rsqrtf(var + 1e-5f);
    const float mrs  = mean * rstd;

    const bfrag* wb = (const bfrag*)zpW;
    f4 acc = {0.f, 0.f, 0.f, 0.f};
#pragma unroll
    for (int kb = 0; kb < 4; ++kb)
        acc = __builtin_amdgcn_mfma_f32_16x16x32_bf16(A[kb], wb[kb * 64 + lane],
                                                      acc, 0, 0, 0);
    const float csn = cs16[m], bn = bias16[m];
    float* orow = zp + r0 * 16;
#pragma unroll
    for (int reg = 0; reg < 4; ++reg) {
        const int r = quad * 4 + reg;
        float rs = __shfl(rstd, r, 64);
        float ms = __shfl(mrs, r, 64);
        orow[r * 16 + m] = rs * acc[reg] - ms * csn + bn;
    }
}

// ---------------------------------------------------------------------------
// Kernel 5: fused feat GEMM + catk.  One wave per 16 atoms, grid 256.
//   q = feats@W_feat+b (MFMA K=384 bf16 + f32 rank-4 pos/charge epilogue)
//   c = q + s2c[tok];  acq/ack = relu(c)@Wcq/Wck (LDS round-trip, MFMA)
// ---------------------------------------------------------------------------
__global__ __launch_bounds__(64) void featcatk_kernel(
    const float* __restrict__ pos, const float* __restrict__ charge,
    const float* __restrict__ elem, const float* __restrict__ namec,
    const float* __restrict__ Wf, const float* __restrict__ bf,
    const float* __restrict__ s2c, const int* __restrict__ tok,
    const short* __restrict__ featW, const short* __restrict__ WcqF,
    const short* __restrict__ WckF, float* __restrict__ q_out,
    float* __restrict__ c_out, float* __restrict__ acq,
    float* __restrict__ ack) {
    __shared__ short ctile[16 * 136];   // relu(c) bf16, 272 B rows
    const int lane = threadIdx.x;
    const int m = lane & 15, quad = lane >> 4;
    const int a0 = blockIdx.x * 16;

    f4 acc[8];
#pragma unroll
    for (int nt = 0; nt < 8; ++nt) acc[nt] = (f4){0.f, 0.f, 0.f, 0.f};
    const bfrag* Bb = (const bfrag*)featW;
#pragma unroll
    for (int kb = 0; kb < 12; ++kb) {
        const int f0 = kb * 32 + quad * 8;          // feature offset - 4
        const float* src = (kb < 4)
            ? (elem + (size_t)(a0 + m) * 128 + f0)
            : (namec + (size_t)(a0 + m) * 256 + f0 - 128);
        float4 x0 = ((const float4*)src)[0];
        float4 x1 = ((const float4*)src)[1];
        bfrag A;
        A[0] = f2bf(x0.x); A[1] = f2bf(x0.y); A[2] = f2bf(x0.z); A[3] = f2bf(x0.w);
        A[4] = f2bf(x1.x); A[5] = f2bf(x1.y); A[6] = f2bf(x1.z); A[7] = f2bf(x1.w);
#pragma unroll
        for (int nt = 0; nt < 8; ++nt)
            acc[nt] = __builtin_amdgcn_mfma_f32_16x16x32_bf16(
                A, Bb[(kb * 8 + nt) * 64 + lane], acc[nt], 0, 0, 0);
    }
    // epilogue: rows r = quad*4+reg (atoms a0+r), col cn = nt*16+m
    float px[4], py[4], pz[4], ch[4];
    int tk4[4];
#pragma unroll
    for (int reg = 0; reg < 4; ++reg) {
        const int a = a0 + quad * 4 + reg;
        px[reg] = pos[a * 3 + 0]; py[reg] = pos[a * 3 + 1];
        pz[reg] = pos[a * 3 + 2]; ch[reg] = charge[a];
        tk4[reg] = tok[a];
    }
#pragma unroll
    for (int nt = 0; nt < 8; ++nt) {
        const int cn = nt * 16 + m;
        const float w0 = Wf[cn], w1 = Wf[128 + cn], w2 = Wf[256 + cn],
                    w3 = Wf[384 + cn], bv = bf[cn];
#pragma unroll
        for (int reg = 0; reg < 4; ++reg) {
            const int r = quad * 4 + reg;
            float qv = acc[nt][reg] + px[reg] * w0 + py[reg] * w1 +
                       pz[reg] * w2 + ch[reg] * w3 + bv;
            q_out[(size_t)(a0 + r) * 128 + cn] = qv;
            float cv = qv + s2c[(size_t)tk4[reg] * 128 + cn];
            c_out[(size_t)(a0 + r) * 128 + cn] = cv;
            ctile[r * 136 + cn] = f2bf(fmaxf(cv, 0.f));
        }
    }
    __syncthreads();
    // catk GEMM: acq/ack = relu(c) @ Wcq/Wck
    f4 a2[2] = {{0.f, 0.f, 0.f, 0.f}, {0.f, 0.f, 0.f, 0.f}};
    const bfrag* Bq = (const bfrag*)WcqF;
    const bfrag* Bk = (const bfrag*)WckF;
#pragma unroll
    for (int kb = 0; kb < 4; ++kb) {
        bfrag Af = *(const bfrag*)&ctile[m * 136 + kb * 32 + quad * 8];
        a2[0] = __builtin_amdgcn_mfma_f32_16x16x32_bf16(Af, Bq[kb * 64 + lane],
                                                        a2[0], 0, 0, 0);
        a2[1] = __builtin_amdgcn_mfma_f32_16x16x32_bf16(Af, Bk[kb * 64 + lane],
                                                        a2[1], 0, 0, 0);
    }
#pragma unroll
    for (int reg = 0; reg < 4; ++reg) {
        const int r = quad * 4 + reg;
        acq[(size_t)(a0 + r) * 16 + m] = a2[0][reg];
        ack[(size_t)(a0 + r) * 16 + m] = a2[1][reg];
    }
}

// ---------------------------------------------------------------------------
// Kernel 6: pair tensor via LDS-free MFMA MLP chain.
// One wave per q-atom, 4 waves/block, grid 1024. 8 groups of 16 slots.
// kappa-slot trick: real dim d -> k-slot (d>>2)*8+(d&3); j=4..7 zeroed.
// ---------------------------------------------------------------------------
__global__ __launch_bounds__(256) void pair_mfma_kernel(
    const float* __restrict__ pos, const int* __restrict__ uid,
    const int* __restrict__ tok, const float* __restrict__ zp,
    const float* __restrict__ acq, const float* __restrict__ ack,
    const float* __restrict__ W_pos, const float* __restrict__ W_dist,
    const float* __restrict__ W_mask, const float* __restrict__ W_m1,
    const float* __restrict__ W_m2, const float* __restrict__ W_m3,
    float* __restrict__ p_out) {
    const int wave = threadIdx.x >> 6, lane = threadIdx.x & 63;
    const int m = lane & 15, quad = lane >> 4;
    const int qa = blockIdx.x * 4 + wave;
    const int j = qa >> 5;

    // MLP weight A-frags: A[m][k], k=quad*8+jj -> W[quad*4+jj][m] (jj<4)
    bfrag A1, A2, A3;
#pragma unroll
    for (int jj = 0; jj < 4; ++jj) {
        const int d = quad * 4 + jj;
        A1[jj] = f2bf(W_m1[d * 16 + m]); A1[jj + 4] = 0;
        A2[jj] = f2bf(W_m2[d * 16 + m]); A2[jj + 4] = 0;
        A3[jj] = f2bf(W_m3[d * 16 + m]); A3[jj + 4] = 0;
    }
    // geometry weights for this lane's dims
    float wp0[4], wp1[4], wp2[4], wd[4], wm[4];
#pragma unroll
    for (int jj = 0; jj < 4; ++jj) {
        const int d = quad * 4 + jj;
        wp0[jj] = W_pos[d]; wp1[jj] = W_pos[16 + d]; wp2[jj] = W_pos[32 + d];
        wd[jj] = W_dist[d]; wm[jj] = W_mask[d];
    }
    const float pqx = pos[qa * 3 + 0], pqy = pos[qa * 3 + 1],
                pqz = pos[qa * 3 + 2];
    const int uq = uid[qa], tq = tok[qa];
    const float4 aq = *(const float4*)(acq + (size_t)qa * 16 + quad * 4);
    const float aqv[4] = {aq.x, aq.y, aq.z, aq.w};
    float* pbase = p_out + (size_t)qa * 2048;

    const f4 zero = {0.f, 0.f, 0.f, 0.f};
#pragma unroll
    for (int g = 0; g < 8; ++g) {
        const int kk = g * 16 + m;
        const int src = j * 32 + kk - 48;
        const bool valid = ((unsigned)src < (unsigned)N_ATOMS);
        float dx = 0.f, dy = 0.f, dz = 0.f, dn = 0.f, vflag = 0.f;
        float zv[4] = {0.f, 0.f, 0.f, 0.f}, av[4] = {0.f, 0.f, 0.f, 0.f};
        if (valid) {
            dx = pos[src * 3 + 0] - pqx;
            dy = pos[src * 3 + 1] - pqy;
            dz = pos[src * 3 + 2] - pqz;
            dn = 1.f / (1.f + dx * dx + dy * dy + dz * dz);
            vflag = (uid[src] == uq) ? 1.f : 0.f;
            const int tk_ = tok[src];
            float4 zl = *(const float4*)(zp + ((size_t)tq * 512 + tk_) * 16 + quad * 4);
            float4 al = *(const float4*)(ack + (size_t)src * 16 + quad * 4);
            zv[0] = zl.x; zv[1] = zl.y; zv[2] = zl.z; zv[3] = zl.w;
            av[0] = al.x; av[1] = al.y; av[2] = al.z; av[3] = al.w;
        }
        float pb[4];
        bfrag B;
#pragma unroll
        for (int jj = 0; jj < 4; ++jj) {
            float t = dx * wp0[jj] + dy * wp1[jj] + dz * wp2[jj] +
                      dn * wd[jj] + wm[jj];
            pb[jj] = vflag * t + zv[jj] + av[jj] + aqv[jj];
            B[jj] = f2bf(fmaxf(pb[jj], 0.f));
            B[jj + 4] = 0;
        }
        f4 t1 = __builtin_amdgcn_mfma_f32_16x16x32_bf16(A1, B, zero, 0, 0, 0);
        bfrag B2;
#pragma unroll
        for (int jj = 0; jj < 4; ++jj) {
            B2[jj] = f2bf(fmaxf(t1[jj], 0.f)); B2[jj + 4] = 0;
        }
        f4 t2 = __builtin_amdgcn_mfma_f32_16x16x32_bf16(A2, B2, zero, 0, 0, 0);
        bfrag B3;
#pragma unroll
        for (int jj = 0; jj < 4; ++jj) {
            B3[jj] = f2bf(fmaxf(t2[jj], 0.f)); B3[jj + 4] = 0;
        }
        f4 t3 = __builtin_amdgcn_mfma_f32_16x16x32_bf16(A3, B3, zero, 0, 0, 0);
        float4 o = make_float4(pb[0] + t3[0], pb[1] + t3[1],
                               pb[2] + t3[2], pb[3] + t3[3]);
        *(float4*)(pbase + kk * 16 + quad * 4) = o;
    }
}

// ---------------------------------------------------------------------------
extern "C" void kernel_launch(void* const* d_in, const int* in_sizes, int n_in,
                              void* d_out, int out_size, void* d_ws, size_t ws_size,
                              hipStream_t stream) {
    const float* ref_pos     = (const float*)d_in[0];
    const float* ref_charge  = (const float*)d_in[1];
    const float* ref_element = (const float*)d_in[2];
    const float* ref_name    = (const float*)d_in[3];
    const int*   uid         = (const int*)d_in[5];
    const float* a2t         = (const float*)d_in[6];
    const float* s_trunk     = (const float*)d_in[7];
    const float* z           = (const float*)d_in[8];
    const float* W_feat      = (const float*)d_in[9];
    const float* b_feat      = (const float*)d_in[10];
    const float* W_pos       = (const float*)d_in[11];
    const float* W_dist      = (const float*)d_in[12];
    const float* W_mask      = (const float*)d_in[13];
    const float* ln_s_g      = (const float*)d_in[14];
    const float* ln_s_b      = (const float*)d_in[15];
    const float* W_s2c       = (const float*)d_in[16];
    const float* ln_z_g      = (const float*)d_in[17];
    const float* ln_z_b      = (const float*)d_in[18];
    const float* W_z2p       = (const float*)d_in[19];
    const float* W_cq        = (const float*)d_in[20];
    const float* W_ck        = (const float*)d_in[21];
    const float* W_m1        = (const float*)d_in[22];
    const float* W_m2        = (const float*)d_in[23];
    const float* W_m3        = (const float*)d_in[24];

    float* out = (float*)d_out;
    float* q_out = out;                        // 4096*128
    float* c_out = out + 524288;               // 4096*128
    float* p_out = out + 1048576;              // 128*32*128*16

    float* zp   = (float*)d_ws;                // 4194304 floats
    float* s2c  = zp + 4194304;                // 65536
    float* acq  = s2c + 65536;                 // 65536
    float* ack  = acq + 65536;                 // 65536
    int*   tok  = (int*)(ack + 65536);         // 4096 ints
    short* zpW   = (short*)(tok + 4096);       // 2048 bf16
    short* featW = zpW + 2048;                 // 49152 bf16
    short* WcqF  = featW + 49152;              // 2048 bf16
    short* WckF  = WcqF + 2048;                // 2048 bf16
    float* bias16 = (float*)(WckF + 2048);     // 16
    float* cs16   = bias16 + 16;               // 16

    tok_kernel<<<1024, 256, 0, stream>>>(a2t, tok);
    prep_kernel<<<28, 256, 0, stream>>>(W_z2p, ln_z_g, ln_z_b, W_feat,
                                        W_cq, W_ck, zpW, featW, WcqF, WckF,
                                        bias16, cs16);
    s2c_kernel<<<64, 128, 0, stream>>>(s_trunk, ln_s_g, ln_s_b, W_s2c, s2c);
    zp_mfma_kernel<<<4096, 256, 0, stream>>>(z, zpW, bias16, cs16, zp);
    featcatk_kernel<<<256, 64, 0, stream>>>(ref_pos, ref_charge, ref_element,
                                            ref_name, W_feat, b_feat, s2c, tok,
                                            featW, WcqF, WckF,
                                            q_out, c_out, acq, ack);
    pair_mfma_kernel<<<1024, 256, 0, stream>>>(ref_pos, uid, tok, zp, acq, ack,
                                               W_pos, W_dist, W_mask,
                                               W_m1, W_m2, W_m3, p_out);
}

// Round 4
// 293.273 us; speedup vs baseline: 4.1418x; 1.1163x over previous
//
#include <hip/hip_runtime.h>

#define N_ATOMS 4096
#define T_TOK   512
#define TOKEN_S 384
#define TOKEN_Z 128

using bfrag = __attribute__((ext_vector_type(8))) short;   // 8 bf16 (4 VGPRs)
using f4    = __attribute__((ext_vector_type(4))) float;

__device__ __forceinline__ short f2bf(float f) {
    unsigned u = __float_as_uint(f);
    unsigned r = u + 0x7FFFu + ((u >> 16) & 1u);   // RNE
    return (short)(r >> 16);
}
__device__ __forceinline__ float bf2f(unsigned short s) {
    return __uint_as_float(((unsigned)s) << 16);
}

// ---------------------------------------------------------------------------
// setup_kernel: merged tok extraction + all weight-fragment prep + reductions.
// blocks 0..50   : bf16 B-frag builders, fs = blk*4 + (tid>>6):
//                  fs 0..3 zpW | 4..99 featW | 100..103 WcqF | 104..107 WckF
//                  | 108..203 s2cW
// block 51       : bias16[n]=sum_k bz[k]Wz[k][n]; cs16[n]=sum_k gz[k]Wz[k][n]
// block 52       : cs128[o]=sum_k gs[k]Ws2c[k][o]; bs128[o]=sum_k bs[k]Ws2c[k][o]
// blocks 53..1076: tok from one-hot a2t (one wave per atom)
// ---------------------------------------------------------------------------
__global__ __launch_bounds__(256) void setup_kernel(
    const float* __restrict__ a2t, const float* __restrict__ Wz,
    const float* __restrict__ gz, const float* __restrict__ bz,
    const float* __restrict__ Wf, const float* __restrict__ Wcq,
    const float* __restrict__ Wck, const float* __restrict__ Ws2c,
    const float* __restrict__ gs, const float* __restrict__ bs,
    int* __restrict__ tok, short* __restrict__ zpW,
    short* __restrict__ featW, short* __restrict__ WcqF,
    short* __restrict__ WckF, short* __restrict__ s2cW,
    float* __restrict__ bias16, float* __restrict__ cs16,
    float* __restrict__ cs128, float* __restrict__ bs128) {
    const int b = blockIdx.x, tid = threadIdx.x;
    if (b >= 53) {                      // tok
        const int wave = tid >> 6, lane = tid & 63;
        const int n = (b - 53) * 4 + wave;
        const float* row = a2t + (size_t)n * T_TOK;
        int found = 0;
#pragma unroll
        for (int m = 0; m < T_TOK / 64; ++m)
            if (row[lane + 64 * m] > 0.5f) found = lane + 64 * m;
#pragma unroll
        for (int off = 32; off >= 1; off >>= 1)
            found = max(found, __shfl_xor(found, off, 64));
        if (lane == 0) tok[n] = found;
        return;
    }
    if (b == 51) {                      // bias16 / cs16, 8 threads per output
        const int o = tid >> 3, s = tid & 7;
        const float* vec = (o < 16) ? bz : gz;
        const int n = o & 15;
        float p = 0.f;
#pragma unroll
        for (int i = 0; i < 16; ++i) {
            const int k = s + 8 * i;
            p += vec[k] * Wz[k * 16 + n];
        }
        p += __shfl_xor(p, 1, 64); p += __shfl_xor(p, 2, 64);
        p += __shfl_xor(p, 4, 64);
        if (s == 0) { if (o < 16) bias16[n] = p; else cs16[n] = p; }
        return;
    }
    if (b == 52) {                      // cs128 / bs128
        const int o = tid & 127, arr = tid >> 7;
        const float* vec = arr ? bs : gs;
        float s = 0.f;
        for (int k = 0; k < TOKEN_S; ++k)
            s += vec[k] * Ws2c[(size_t)k * 128 + o];
        if (arr) bs128[o] = s; else cs128[o] = s;
        return;
    }
    // frag builders
    const int id = b * 256 + tid;
    const int lane = id & 63, fs = id >> 6;
    const int quad = lane >> 4, n = lane & 15;
    short v[8];
    short* dst;
    if (fs < 4) {                       // zp weights: g*Wz
#pragma unroll
        for (int j = 0; j < 8; ++j) {
            int k = fs * 32 + quad * 8 + j;
            v[j] = f2bf(gz[k] * Wz[k * 16 + n]);
        }
        dst = zpW + (size_t)(fs * 64 + lane) * 8;
    } else if (fs < 100) {              // feat weights rows 4..387
        const int idx = fs - 4, kb = idx >> 3, nt = idx & 7;
#pragma unroll
        for (int j = 0; j < 8; ++j) {
            int f = 4 + kb * 32 + quad * 8 + j;
            v[j] = f2bf(Wf[(size_t)f * 128 + nt * 16 + n]);
        }
        dst = featW + (size_t)(idx * 64 + lane) * 8;
    } else if (fs < 104) {              // W_cq
        const int kb = fs - 100;
#pragma unroll
        for (int j = 0; j < 8; ++j) {
            int k = kb * 32 + quad * 8 + j;
            v[j] = f2bf(Wcq[k * 16 + n]);
        }
        dst = WcqF + (size_t)(kb * 64 + lane) * 8;
    } else if (fs < 108) {              // W_ck
        const int kb = fs - 104;
#pragma unroll
        for (int j = 0; j < 8; ++j) {
            int k = kb * 32 + quad * 8 + j;
            v[j] = f2bf(Wck[k * 16 + n]);
        }
        dst = WckF + (size_t)(kb * 64 + lane) * 8;
    } else {                            // s2c weights: gs*Ws2c
        const int idx = fs - 108, kb = idx >> 3, nt = idx & 7;
#pragma unroll
        for (int j = 0; j < 8; ++j) {
            int k = kb * 32 + quad * 8 + j;
            v[j] = f2bf(gs[k] * Ws2c[(size_t)k * 128 + nt * 16 + n]);
        }
        dst = s2cW + (size_t)(idx * 64 + lane) * 8;
    }
#pragma unroll
    for (int j = 0; j < 8; ++j) dst[j] = v[j];
}

// ---------------------------------------------------------------------------
// s2c = LN(s_trunk) @ W_s2c via MFMA, LN folded:
//   y[r,cn] = rstd_r*(x@gW)[r,cn] - rstd_r*mu_r*cs128[cn] + bs128[cn]
// grid 64 x 256: wave wg = blk*4+wave; tile = wg>>3 (16 tokens), nt = wg&7.
// ---------------------------------------------------------------------------
__global__ __launch_bounds__(256) void s2c_mfma_kernel(
    const float* __restrict__ s_trunk, const short* __restrict__ s2cW,
    const float* __restrict__ cs128, const float* __restrict__ bs128,
    float* __restrict__ s2c) {
    const int wave = threadIdx.x >> 6, lane = threadIdx.x & 63;
    const int m = lane & 15, quad = lane >> 4;
    const int wg = blockIdx.x * 4 + wave;
    const int tile = wg >> 3, nt = wg & 7;
    const int t0 = tile * 16;
    const float* xrow = s_trunk + (size_t)(t0 + m) * TOKEN_S;

    bfrag A[12];
    float xs = 0.f, xq = 0.f;
#pragma unroll
    for (int kb = 0; kb < 12; ++kb) {
        const float4* p = (const float4*)(xrow + kb * 32 + quad * 8);
        float4 x0 = p[0], x1 = p[1];
        const float xv[8] = {x0.x, x0.y, x0.z, x0.w, x1.x, x1.y, x1.z, x1.w};
#pragma unroll
        for (int j = 0; j < 8; ++j) {
            A[kb][j] = f2bf(xv[j]);
            xs += xv[j]; xq = fmaf(xv[j], xv[j], xq);
        }
    }
    xs += __shfl_xor(xs, 16, 64); xs += __shfl_xor(xs, 32, 64);
    xq += __shfl_xor(xq, 16, 64); xq += __shfl_xor(xq, 32, 64);
    const float mean = xs * (1.f / TOKEN_S);
    const float var  = xq * (1.f / TOKEN_S) - mean * mean;
    const float rstd = rsqrtf(var + 1e-5f);
    const float mrs  = mean * rstd;

    const bfrag* Bb = (const bfrag*)s2cW;
    f4 acc = {0.f, 0.f, 0.f, 0.f};
#pragma unroll
    for (int kb = 0; kb < 12; ++kb)
        acc = __builtin_amdgcn_mfma_f32_16x16x32_bf16(
            A[kb], Bb[(kb * 8 + nt) * 64 + lane], acc, 0, 0, 0);

    const int cn = nt * 16 + m;
    const float csn = cs128[cn], bsn = bs128[cn];
#pragma unroll
    for (int reg = 0; reg < 4; ++reg) {
        const int r = quad * 4 + reg;
        const float rs = __shfl(rstd, r, 64);
        const float ms = __shfl(mrs, r, 64);
        s2c[(size_t)(t0 + r) * 128 + cn] = rs * acc[reg] - ms * csn + bsn;
    }
}

// ---------------------------------------------------------------------------
// zp = LN(z) @ W' + bias via MFMA, folded LN, bf16 OUTPUT.
// Direct frag-order global loads (no LDS). One wave per 16-row tile.
// ---------------------------------------------------------------------------
__global__ __launch_bounds__(256) void zp_mfma_kernel(
    const float* __restrict__ z, const short* __restrict__ zpW,
    const float* __restrict__ bias16, const float* __restrict__ cs16,
    unsigned short* __restrict__ zp_bf) {
    const int wave = threadIdx.x >> 6, lane = threadIdx.x & 63;
    const int m = lane & 15, quad = lane >> 4;
    const size_t r0 = ((size_t)blockIdx.x * 4 + wave) * 16;
    const float* zrow = z + (r0 + m) * (size_t)TOKEN_Z;

    bfrag A[4];
    float xs = 0.f, xq = 0.f;
#pragma unroll
    for (int kb = 0; kb < 4; ++kb) {
        const float4* p = (const float4*)(zrow + kb * 32 + quad * 8);
        float4 x0 = p[0], x1 = p[1];
        const float xv[8] = {x0.x, x0.y, x0.z, x0.w, x1.x, x1.y, x1.z, x1.w};
#pragma unroll
        for (int j = 0; j < 8; ++j) {
            A[kb][j] = f2bf(xv[j]);
            xs += xv[j]; xq = fmaf(xv[j], xv[j], xq);
        }
    }
    xs += __shfl_xor(xs, 16, 64); xs += __shfl_xor(xs, 32, 64);
    xq += __shfl_xor(xq, 16, 64); xq += __shfl_xor(xq, 32, 64);
    const float mean = xs * (1.f / TOKEN_Z);
    const float var  = xq * (1.f / TOKEN_Z) - mean * mean;
    const float rstd = rsqrtf(var + 1e-5f);
    const float mrs  = mean * rstd;

    const bfrag* wb = (const bfrag*)zpW;
    f4 acc = {0.f, 0.f, 0.f, 0.f};
#pragma unroll
    for (int kb = 0; kb < 4; ++kb)
        acc = __builtin_amdgcn_mfma_f32_16x16x32_bf16(A[kb], wb[kb * 64 + lane],
                                                      acc, 0, 0, 0);
    const float csn = cs16[m], bn = bias16[m];
#pragma unroll
    for (int reg = 0; reg < 4; ++reg) {
        const int r = quad * 4 + reg;
        const float rs = __shfl(rstd, r, 64);
        const float ms = __shfl(mrs, r, 64);
        zp_bf[(r0 + r) * 16 + m] =
            (unsigned short)f2bf(rs * acc[reg] - ms * csn + bn);
    }
}

// ---------------------------------------------------------------------------
// featcatk v2: block 128 (2 waves), grid 256 (16 atoms per block).
// wave w handles n-tiles w*4..w*4+3 of the K=384 feat GEMM; then
// wave0 -> acq (Wcq), wave1 -> ack (Wck) on the shared relu(c) tile.
// ---------------------------------------------------------------------------
__global__ __launch_bounds__(128) void featcatk_kernel(
    const float* __restrict__ pos, const float* __restrict__ charge,
    const float* __restrict__ elem, const float* __restrict__ namec,
    const float* __restrict__ Wf, const float* __restrict__ bf,
    const float* __restrict__ s2c, const int* __restrict__ tok,
    const short* __restrict__ featW, const short* __restrict__ WcqF,
    const short* __restrict__ WckF, float* __restrict__ q_out,
    float* __restrict__ c_out, float* __restrict__ acq,
    float* __restrict__ ack) {
    __shared__ short ctile[16 * 136];
    const int wave = threadIdx.x >> 6, lane = threadIdx.x & 63;
    const int m = lane & 15, quad = lane >> 4;
    const int a0 = blockIdx.x * 16;
    const int ntb = wave * 4;

    f4 acc[4];
#pragma unroll
    for (int nt = 0; nt < 4; ++nt) acc[nt] = (f4){0.f, 0.f, 0.f, 0.f};
    const bfrag* Bb = (const bfrag*)featW;
#pragma unroll
    for (int kb = 0; kb < 12; ++kb) {
        const int f0 = kb * 32 + quad * 8;
        const float* src = (kb < 4)
            ? (elem + (size_t)(a0 + m) * 128 + f0)
            : (namec + (size_t)(a0 + m) * 256 + f0 - 128);
        float4 x0 = ((const float4*)src)[0];
        float4 x1 = ((const float4*)src)[1];
        bfrag A;
        A[0] = f2bf(x0.x); A[1] = f2bf(x0.y); A[2] = f2bf(x0.z); A[3] = f2bf(x0.w);
        A[4] = f2bf(x1.x); A[5] = f2bf(x1.y); A[6] = f2bf(x1.z); A[7] = f2bf(x1.w);
#pragma unroll
        for (int nt = 0; nt < 4; ++nt)
            acc[nt] = __builtin_amdgcn_mfma_f32_16x16x32_bf16(
                A, Bb[(kb * 8 + ntb + nt) * 64 + lane], acc[nt], 0, 0, 0);
    }
    float px[4], py[4], pz[4], ch[4];
    int tk4[4];
#pragma unroll
    for (int reg = 0; reg < 4; ++reg) {
        const int a = a0 + quad * 4 + reg;
        px[reg] = pos[a * 3 + 0]; py[reg] = pos[a * 3 + 1];
        pz[reg] = pos[a * 3 + 2]; ch[reg] = charge[a];
        tk4[reg] = tok[a];
    }
#pragma unroll
    for (int nt = 0; nt < 4; ++nt) {
        const int cn = (ntb + nt) * 16 + m;
        const float w0 = Wf[cn], w1 = Wf[128 + cn], w2 = Wf[256 + cn],
                    w3 = Wf[384 + cn], bv = bf[cn];
#pragma unroll
        for (int reg = 0; reg < 4; ++reg) {
            const int r = quad * 4 + reg;
            float qv = acc[nt][reg] + px[reg] * w0 + py[reg] * w1 +
                       pz[reg] * w2 + ch[reg] * w3 + bv;
            q_out[(size_t)(a0 + r) * 128 + cn] = qv;
            float cv = qv + s2c[(size_t)tk4[reg] * 128 + cn];
            c_out[(size_t)(a0 + r) * 128 + cn] = cv;
            ctile[r * 136 + cn] = f2bf(fmaxf(cv, 0.f));
        }
    }
    __syncthreads();
    const bfrag* BW = wave ? (const bfrag*)WckF : (const bfrag*)WcqF;
    float* dst = wave ? ack : acq;
    f4 a2 = {0.f, 0.f, 0.f, 0.f};
#pragma unroll
    for (int kb = 0; kb < 4; ++kb) {
        bfrag Af = *(const bfrag*)&ctile[m * 136 + kb * 32 + quad * 8];
        a2 = __builtin_amdgcn_mfma_f32_16x16x32_bf16(Af, BW[kb * 64 + lane],
                                                     a2, 0, 0, 0);
    }
#pragma unroll
    for (int reg = 0; reg < 4; ++reg)
        dst[(size_t)(a0 + quad * 4 + reg) * 16 + m] = a2[reg];
}

// ---------------------------------------------------------------------------
// pair tensor via LDS-free MFMA MLP chain (zp input now bf16).
// ---------------------------------------------------------------------------
__global__ __launch_bounds__(256) void pair_mfma_kernel(
    const float* __restrict__ pos, const int* __restrict__ uid,
    const int* __restrict__ tok, const unsigned short* __restrict__ zp_bf,
    const float* __restrict__ acq, const float* __restrict__ ack,
    const float* __restrict__ W_pos, const float* __restrict__ W_dist,
    const float* __restrict__ W_mask, const float* __restrict__ W_m1,
    const float* __restrict__ W_m2, const float* __restrict__ W_m3,
    float* __restrict__ p_out) {
    const int wave = threadIdx.x >> 6, lane = threadIdx.x & 63;
    const int m = lane & 15, quad = lane >> 4;
    const int qa = blockIdx.x * 4 + wave;
    const int j = qa >> 5;

    bfrag A1, A2, A3;
#pragma unroll
    for (int jj = 0; jj < 4; ++jj) {
        const int d = quad * 4 + jj;
        A1[jj] = f2bf(W_m1[d * 16 + m]); A1[jj + 4] = 0;
        A2[jj] = f2bf(W_m2[d * 16 + m]); A2[jj + 4] = 0;
        A3[jj] = f2bf(W_m3[d * 16 + m]); A3[jj + 4] = 0;
    }
    float wp0[4], wp1[4], wp2[4], wd[4], wm[4];
#pragma unroll
    for (int jj = 0; jj < 4; ++jj) {
        const int d = quad * 4 + jj;
        wp0[jj] = W_pos[d]; wp1[jj] = W_pos[16 + d]; wp2[jj] = W_pos[32 + d];
        wd[jj] = W_dist[d]; wm[jj] = W_mask[d];
    }
    const float pqx = pos[qa * 3 + 0], pqy = pos[qa * 3 + 1],
                pqz = pos[qa * 3 + 2];
    const int uq = uid[qa], tq = tok[qa];
    const float4 aq = *(const float4*)(acq + (size_t)qa * 16 + quad * 4);
    const float aqv[4] = {aq.x, aq.y, aq.z, aq.w};
    float* pbase = p_out + (size_t)qa * 2048;

    const f4 zero = {0.f, 0.f, 0.f, 0.f};
#pragma unroll
    for (int g = 0; g < 8; ++g) {
        const int kk = g * 16 + m;
        const int src = j * 32 + kk - 48;
        const bool valid = ((unsigned)src < (unsigned)N_ATOMS);
        float dx = 0.f, dy = 0.f, dz = 0.f, dn = 0.f, vflag = 0.f;
        float zv[4] = {0.f, 0.f, 0.f, 0.f}, av[4] = {0.f, 0.f, 0.f, 0.f};
        if (valid) {
            dx = pos[src * 3 + 0] - pqx;
            dy = pos[src * 3 + 1] - pqy;
            dz = pos[src * 3 + 2] - pqz;
            dn = 1.f / (1.f + dx * dx + dy * dy + dz * dz);
            vflag = (uid[src] == uq) ? 1.f : 0.f;
            const int tk_ = tok[src];
            ushort4 zl = *(const ushort4*)(zp_bf +
                            ((size_t)tq * 512 + tk_) * 16 + quad * 4);
            float4 al = *(const float4*)(ack + (size_t)src * 16 + quad * 4);
            zv[0] = bf2f(zl.x); zv[1] = bf2f(zl.y);
            zv[2] = bf2f(zl.z); zv[3] = bf2f(zl.w);
            av[0] = al.x; av[1] = al.y; av[2] = al.z; av[3] = al.w;
        }
        float pb[4];
        bfrag B;
#pragma unroll
        for (int jj = 0; jj < 4; ++jj) {
            float t = dx * wp0[jj] + dy * wp1[jj] + dz * wp2[jj] +
                      dn * wd[jj] + wm[jj];
            pb[jj] = vflag * t + zv[jj] + av[jj] + aqv[jj];
            B[jj] = f2bf(fmaxf(pb[jj], 0.f));
            B[jj + 4] = 0;
        }
        f4 t1 = __builtin_amdgcn_mfma_f32_16x16x32_bf16(A1, B, zero, 0, 0, 0);
        bfrag B2;
#pragma unroll
        for (int jj = 0; jj < 4; ++jj) {
            B2[jj] = f2bf(fmaxf(t1[jj], 0.f)); B2[jj + 4] = 0;
        }
        f4 t2 = __builtin_amdgcn_mfma_f32_16x16x32_bf16(A2, B2, zero, 0, 0, 0);
        bfrag B3;
#pragma unroll
        for (int jj = 0; jj < 4; ++jj) {
            B3[jj] = f2bf(fmaxf(t2[jj], 0.f)); B3[jj + 4] = 0;
        }
        f4 t3 = __builtin_amdgcn_mfma_f32_16x16x32_bf16(A3, B3, zero, 0, 0, 0);
        float4 o = make_float4(pb[0] + t3[0], pb[1] + t3[1],
                               pb[2] + t3[2], pb[3] + t3[3]);
        *(float4*)(pbase + kk * 16 + quad * 4) = o;
    }
}

// ---------------------------------------------------------------------------
extern "C" void kernel_launch(void* const* d_in, const int* in_sizes, int n_in,
                              void* d_out, int out_size, void* d_ws, size_t ws_size,
                              hipStream_t stream) {
    const float* ref_pos     = (const float*)d_in[0];
    const float* ref_charge  = (const float*)d_in[1];
    const float* ref_element = (const float*)d_in[2];
    const float* ref_name    = (const float*)d_in[3];
    const int*   uid         = (const int*)d_in[5];
    const float* a2t         = (const float*)d_in[6];
    const float* s_trunk     = (const float*)d_in[7];
    const float* z           = (const float*)d_in[8];
    const float* W_feat      = (const float*)d_in[9];
    const float* b_feat      = (const float*)d_in[10];
    const float* W_pos       = (const float*)d_in[11];
    const float* W_dist      = (const float*)d_in[12];
    const float* W_mask      = (const float*)d_in[13];
    const float* ln_s_g      = (const float*)d_in[14];
    const float* ln_s_b      = (const float*)d_in[15];
    const float* W_s2c       = (const float*)d_in[16];
    const float* ln_z_g      = (const float*)d_in[17];
    const float* ln_z_b      = (const float*)d_in[18];
    const float* W_z2p       = (const float*)d_in[19];
    const float* W_cq        = (const float*)d_in[20];
    const float* W_ck        = (const float*)d_in[21];
    const float* W_m1        = (const float*)d_in[22];
    const float* W_m2        = (const float*)d_in[23];
    const float* W_m3        = (const float*)d_in[24];

    float* out = (float*)d_out;
    float* q_out = out;                        // 4096*128
    float* c_out = out + 524288;               // 4096*128
    float* p_out = out + 1048576;              // 128*32*128*16

    char* w = (char*)d_ws;
    unsigned short* zp_bf = (unsigned short*)w;      // 4194304 bf16 (8 MB)
    float* s2c  = (float*)(w + 8388608);             // 65536 f32
    float* acq  = s2c + 65536;                       // 65536
    float* ack  = acq + 65536;                       // 65536
    int*   tok  = (int*)(ack + 65536);               // 4096
    short* zpW   = (short*)(tok + 4096);             // 2048
    short* featW = zpW + 2048;                       // 49152
    short* WcqF  = featW + 49152;                    // 2048
    short* WckF  = WcqF + 2048;                      // 2048
    short* s2cW  = WckF + 2048;                      // 49152
    float* bias16 = (float*)(s2cW + 49152);          // 16
    float* cs16   = bias16 + 16;                     // 16
    float* cs128  = cs16 + 16;                       // 128
    float* bs128  = cs128 + 128;                     // 128

    setup_kernel<<<1077, 256, 0, stream>>>(a2t, W_z2p, ln_z_g, ln_z_b,
                                           W_feat, W_cq, W_ck, W_s2c,
                                           ln_s_g, ln_s_b, tok, zpW, featW,
                                           WcqF, WckF, s2cW, bias16, cs16,
                                           cs128, bs128);
    s2c_mfma_kernel<<<64, 256, 0, stream>>>(s_trunk, s2cW, cs128, bs128, s2c);
    zp_mfma_kernel<<<4096, 256, 0, stream>>>(z, zpW, bias16, cs16, zp_bf);
    featcatk_kernel<<<256, 128, 0, stream>>>(ref_pos, ref_charge, ref_element,
                                             ref_name, W_feat, b_feat, s2c, tok,
                                             featW, WcqF, WckF,
                                             q_out, c_out, acq, ack);
    pair_mfma_kernel<<<1024, 256, 0, stream>>>(ref_pos, uid, tok, zp_bf,
                                               acq, ack, W_pos, W_dist, W_mask,
                                               W_m1, W_m2, W_m3, p_out);
}

// Round 5
// 273.731 us; speedup vs baseline: 4.4375x; 1.0714x over previous
//
#include <hip/hip_runtime.h>

#define N_ATOMS 4096
#define T_TOK   512
#define TOKEN_S 384
#define TOKEN_Z 128

using bfrag = __attribute__((ext_vector_type(8))) short;   // 8 bf16 (4 VGPRs)
using f4    = __attribute__((ext_vector_type(4))) float;

__device__ __forceinline__ short f2bf(float f) {
    unsigned u = __float_as_uint(f);
    unsigned r = u + 0x7FFFu + ((u >> 16) & 1u);   // RNE
    return (short)(r >> 16);
}
__device__ __forceinline__ float bf2f(unsigned short s) {
    return __uint_as_float(((unsigned)s) << 16);
}

// ---------------------------------------------------------------------------
// setup_kernel: tok extraction + weight-frag prep + reductions + band init.
// blocks 0..50   : bf16 B-frag builders (zpW/featW/WcqF/WckF/s2cW)
// block 51       : bias16 / cs16
// block 52       : cs128 / bs128 + init lo/hi
// blocks 53..1076: tok from one-hot a2t (one wave per atom)
// ---------------------------------------------------------------------------
__global__ __launch_bounds__(256) void setup_kernel(
    const float* __restrict__ a2t, const float* __restrict__ Wz,
    const float* __restrict__ gz, const float* __restrict__ bz,
    const float* __restrict__ Wf, const float* __restrict__ Wcq,
    const float* __restrict__ Wck, const float* __restrict__ Ws2c,
    const float* __restrict__ gs, const float* __restrict__ bs,
    int* __restrict__ tok, short* __restrict__ zpW,
    short* __restrict__ featW, short* __restrict__ WcqF,
    short* __restrict__ WckF, short* __restrict__ s2cW,
    float* __restrict__ bias16, float* __restrict__ cs16,
    float* __restrict__ cs128, float* __restrict__ bs128,
    int* __restrict__ lo, int* __restrict__ hi) {
    const int b = blockIdx.x, tid = threadIdx.x;
    if (b >= 53) {                      // tok
        const int wave = tid >> 6, lane = tid & 63;
        const int n = (b - 53) * 4 + wave;
        const float* row = a2t + (size_t)n * T_TOK;
        int found = 0;
#pragma unroll
        for (int m = 0; m < T_TOK / 64; ++m)
            if (row[lane + 64 * m] > 0.5f) found = lane + 64 * m;
#pragma unroll
        for (int off = 32; off >= 1; off >>= 1)
            found = max(found, __shfl_xor(found, off, 64));
        if (lane == 0) tok[n] = found;
        return;
    }
    if (b == 51) {                      // bias16 / cs16
        const int o = tid >> 3, s = tid & 7;
        const float* vec = (o < 16) ? bz : gz;
        const int n = o & 15;
        float p = 0.f;
#pragma unroll
        for (int i = 0; i < 16; ++i) {
            const int k = s + 8 * i;
            p += vec[k] * Wz[k * 16 + n];
        }
        p += __shfl_xor(p, 1, 64); p += __shfl_xor(p, 2, 64);
        p += __shfl_xor(p, 4, 64);
        if (s == 0) { if (o < 16) bias16[n] = p; else cs16[n] = p; }
        return;
    }
    if (b == 52) {                      // cs128 / bs128 + band init
        lo[tid] = 0x7FFFFFFF; lo[tid + 256] = 0x7FFFFFFF;
        hi[tid] = -1;         hi[tid + 256] = -1;
        const int o = tid & 127, arr = tid >> 7;
        const float* vec = arr ? bs : gs;
        float s = 0.f;
        for (int k = 0; k < TOKEN_S; ++k)
            s += vec[k] * Ws2c[(size_t)k * 128 + o];
        if (arr) bs128[o] = s; else cs128[o] = s;
        return;
    }
    // frag builders
    const int id = b * 256 + tid;
    const int lane = id & 63, fs = id >> 6;
    const int quad = lane >> 4, n = lane & 15;
    short v[8];
    short* dst;
    if (fs < 4) {                       // zp weights: g*Wz
#pragma unroll
        for (int j = 0; j < 8; ++j) {
            int k = fs * 32 + quad * 8 + j;
            v[j] = f2bf(gz[k] * Wz[k * 16 + n]);
        }
        dst = zpW + (size_t)(fs * 64 + lane) * 8;
    } else if (fs < 100) {              // feat weights rows 4..387
        const int idx = fs - 4, kb = idx >> 3, nt = idx & 7;
#pragma unroll
        for (int j = 0; j < 8; ++j) {
            int f = 4 + kb * 32 + quad * 8 + j;
            v[j] = f2bf(Wf[(size_t)f * 128 + nt * 16 + n]);
        }
        dst = featW + (size_t)(idx * 64 + lane) * 8;
    } else if (fs < 104) {              // W_cq
        const int kb = fs - 100;
#pragma unroll
        for (int j = 0; j < 8; ++j) {
            int k = kb * 32 + quad * 8 + j;
            v[j] = f2bf(Wcq[k * 16 + n]);
        }
        dst = WcqF + (size_t)(kb * 64 + lane) * 8;
    } else if (fs < 108) {              // W_ck
        const int kb = fs - 104;
#pragma unroll
        for (int j = 0; j < 8; ++j) {
            int k = kb * 32 + quad * 8 + j;
            v[j] = f2bf(Wck[k * 16 + n]);
        }
        dst = WckF + (size_t)(kb * 64 + lane) * 8;
    } else {                            // s2c weights: gs*Ws2c
        const int idx = fs - 108, kb = idx >> 3, nt = idx & 7;
#pragma unroll
        for (int j = 0; j < 8; ++j) {
            int k = kb * 32 + quad * 8 + j;
            v[j] = f2bf(gs[k] * Ws2c[(size_t)k * 128 + nt * 16 + n]);
        }
        dst = s2cW + (size_t)(idx * 64 + lane) * 8;
    }
#pragma unroll
    for (int j = 0; j < 8; ++j) dst[j] = v[j];
}

// ---------------------------------------------------------------------------
// band_kernel: per-token consumed tk range.  src-qa in [-79,+79], tok sorted.
// ---------------------------------------------------------------------------
__global__ __launch_bounds__(256) void band_kernel(
    const int* __restrict__ tok, int* __restrict__ lo, int* __restrict__ hi) {
    const int a = blockIdx.x * 256 + threadIdx.x;
    const int t = tok[a];
    int am = a - 79; if (am < 0) am = 0;
    int ap = a + 79; if (ap > N_ATOMS - 1) ap = N_ATOMS - 1;
    atomicMin(&lo[t], tok[am]);
    atomicMax(&hi[t], tok[ap]);
}

// ---------------------------------------------------------------------------
// worklist_kernel: 1 block x 512. Compact (tq, tk0) tiles (16 tk rows each).
// ---------------------------------------------------------------------------
__global__ __launch_bounds__(512) void worklist_kernel(
    const int* __restrict__ lo, const int* __restrict__ hi,
    int* __restrict__ wl, int* __restrict__ wl_count) {
    __shared__ int scan[512];
    const int t = threadIdx.x;
    const int l = lo[t], h = hi[t];
    const int n = (h >= l) ? ((h - l) >> 4) + 1 : 0;
    scan[t] = n;
    __syncthreads();
    for (int off = 1; off < 512; off <<= 1) {
        int add = (t >= off) ? scan[t - off] : 0;
        __syncthreads();
        scan[t] += add;
        __syncthreads();
    }
    const int off0 = scan[t] - n;
    for (int i = 0; i < n; ++i) {
        int tk0 = l + i * 16;
        if (tk0 > T_TOK - 16) tk0 = T_TOK - 16;
        wl[off0 + i] = (t << 16) | tk0;
    }
    if (t == 511) *wl_count = scan[511];
}

// ---------------------------------------------------------------------------
// s2c = LN(s_trunk) @ W_s2c via MFMA, LN folded into epilogue.
// ---------------------------------------------------------------------------
__global__ __launch_bounds__(256) void s2c_mfma_kernel(
    const float* __restrict__ s_trunk, const short* __restrict__ s2cW,
    const float* __restrict__ cs128, const float* __restrict__ bs128,
    float* __restrict__ s2c) {
    const int wave = threadIdx.x >> 6, lane = threadIdx.x & 63;
    const int m = lane & 15, quad = lane >> 4;
    const int wg = blockIdx.x * 4 + wave;
    const int tile = wg >> 3, nt = wg & 7;
    const int t0 = tile * 16;
    const float* xrow = s_trunk + (size_t)(t0 + m) * TOKEN_S;

    bfrag A[12];
    float xs = 0.f, xq = 0.f;
#pragma unroll
    for (int kb = 0; kb < 12; ++kb) {
        const float4* p = (const float4*)(xrow + kb * 32 + quad * 8);
        float4 x0 = p[0], x1 = p[1];
        const float xv[8] = {x0.x, x0.y, x0.z, x0.w, x1.x, x1.y, x1.z, x1.w};
#pragma unroll
        for (int j = 0; j < 8; ++j) {
            A[kb][j] = f2bf(xv[j]);
            xs += xv[j]; xq = fmaf(xv[j], xv[j], xq);
        }
    }
    xs += __shfl_xor(xs, 16, 64); xs += __shfl_xor(xs, 32, 64);
    xq += __shfl_xor(xq, 16, 64); xq += __shfl_xor(xq, 32, 64);
    const float mean = xs * (1.f / TOKEN_S);
    const float var  = xq * (1.f / TOKEN_S) - mean * mean;
    const float rstd = rsqrtf(var + 1e-5f);
    const float mrs  = mean * rstd;

    const bfrag* Bb = (const bfrag*)s2cW;
    f4 acc = {0.f, 0.f, 0.f, 0.f};
#pragma unroll
    for (int kb = 0; kb < 12; ++kb)
        acc = __builtin_amdgcn_mfma_f32_16x16x32_bf16(
            A[kb], Bb[(kb * 8 + nt) * 64 + lane], acc, 0, 0, 0);

    const int cn = nt * 16 + m;
    const float csn = cs128[cn], bsn = bs128[cn];
#pragma unroll
    for (int reg = 0; reg < 4; ++reg) {
        const int r = quad * 4 + reg;
        const float rs = __shfl(rstd, r, 64);
        const float ms = __shfl(mrs, r, 64);
        s2c[(size_t)(t0 + r) * 128 + cn] = rs * acc[reg] - ms * csn + bsn;
    }
}

// ---------------------------------------------------------------------------
// zp over worklist tiles only: persistent grid, wave-per-tile grid-stride.
// ---------------------------------------------------------------------------
__global__ __launch_bounds__(256) void zp_wl_kernel(
    const float* __restrict__ z, const short* __restrict__ zpW,
    const float* __restrict__ bias16, const float* __restrict__ cs16,
    const int* __restrict__ wl, const int* __restrict__ wl_count,
    unsigned short* __restrict__ zp_bf) {
    const int wave = threadIdx.x >> 6, lane = threadIdx.x & 63;
    const int m = lane & 15, quad = lane >> 4;
    const int nwaves = gridDim.x * 4;
    const int count = *wl_count;
    const bfrag* wb = (const bfrag*)zpW;
    const float csn = cs16[m], bn = bias16[m];

    for (int idx = blockIdx.x * 4 + wave; idx < count; idx += nwaves) {
        const int e = wl[idx];
        const int tq = e >> 16, tk0 = e & 0xFFFF;
        const size_t r0 = (size_t)tq * T_TOK + tk0;
        const float* zrow = z + (r0 + m) * (size_t)TOKEN_Z;

        bfrag A[4];
        float xs = 0.f, xq = 0.f;
#pragma unroll
        for (int kb = 0; kb < 4; ++kb) {
            const float4* p = (const float4*)(zrow + kb * 32 + quad * 8);
            float4 x0 = p[0], x1 = p[1];
            const float xv[8] = {x0.x, x0.y, x0.z, x0.w,
                                 x1.x, x1.y, x1.z, x1.w};
#pragma unroll
            for (int j = 0; j < 8; ++j) {
                A[kb][j] = f2bf(xv[j]);
                xs += xv[j]; xq = fmaf(xv[j], xv[j], xq);
            }
        }
        xs += __shfl_xor(xs, 16, 64); xs += __shfl_xor(xs, 32, 64);
        xq += __shfl_xor(xq, 16, 64); xq += __shfl_xor(xq, 32, 64);
        const float mean = xs * (1.f / TOKEN_Z);
        const float var  = xq * (1.f / TOKEN_Z) - mean * mean;
        const float rstd = rsqrtf(var + 1e-5f);
        const float mrs  = mean * rstd;

        f4 acc = {0.f, 0.f, 0.f, 0.f};
#pragma unroll
        for (int kb = 0; kb < 4; ++kb)
            acc = __builtin_amdgcn_mfma_f32_16x16x32_bf16(
                A[kb], wb[kb * 64 + lane], acc, 0, 0, 0);
#pragma unroll
        for (int reg = 0; reg < 4; ++reg) {
            const int r = quad * 4 + reg;
            const float rs = __shfl(rstd, r, 64);
            const float ms = __shfl(mrs, r, 64);
            zp_bf[(r0 + r) * 16 + m] =
                (unsigned short)f2bf(rs * acc[reg] - ms * csn + bn);
        }
    }
}

// ---------------------------------------------------------------------------
// featcatk: block 128 (2 waves), 16 atoms per block, grid 256.
// ---------------------------------------------------------------------------
__global__ __launch_bounds__(128) void featcatk_kernel(
    const float* __restrict__ pos, const float* __restrict__ charge,
    const float* __restrict__ elem, const float* __restrict__ namec,
    const float* __restrict__ Wf, const float* __restrict__ bf,
    const float* __restrict__ s2c, const int* __restrict__ tok,
    const short* __restrict__ featW, const short* __restrict__ WcqF,
    const short* __restrict__ WckF, float* __restrict__ q_out,
    float* __restrict__ c_out, float* __restrict__ acq,
    float* __restrict__ ack) {
    __shared__ short ctile[16 * 136];
    const int wave = threadIdx.x >> 6, lane = threadIdx.x & 63;
    const int m = lane & 15, quad = lane >> 4;
    const int a0 = blockIdx.x * 16;
    const int ntb = wave * 4;

    f4 acc[4];
#pragma unroll
    for (int nt = 0; nt < 4; ++nt) acc[nt] = (f4){0.f, 0.f, 0.f, 0.f};
    const bfrag* Bb = (const bfrag*)featW;
#pragma unroll
    for (int kb = 0; kb < 12; ++kb) {
        const int f0 = kb * 32 + quad * 8;
        const float* src = (kb < 4)
            ? (elem + (size_t)(a0 + m) * 128 + f0)
            : (namec + (size_t)(a0 + m) * 256 + f0 - 128);
        float4 x0 = ((const float4*)src)[0];
        float4 x1 = ((const float4*)src)[1];
        bfrag A;
        A[0] = f2bf(x0.x); A[1] = f2bf(x0.y); A[2] = f2bf(x0.z); A[3] = f2bf(x0.w);
        A[4] = f2bf(x1.x); A[5] = f2bf(x1.y); A[6] = f2bf(x1.z); A[7] = f2bf(x1.w);
#pragma unroll
        for (int nt = 0; nt < 4; ++nt)
            acc[nt] = __builtin_amdgcn_mfma_f32_16x16x32_bf16(
                A, Bb[(kb * 8 + ntb + nt) * 64 + lane], acc[nt], 0, 0, 0);
    }
    float px[4], py[4], pz[4], ch[4];
    int tk4[4];
#pragma unroll
    for (int reg = 0; reg < 4; ++reg) {
        const int a = a0 + quad * 4 + reg;
        px[reg] = pos[a * 3 + 0]; py[reg] = pos[a * 3 + 1];
        pz[reg] = pos[a * 3 + 2]; ch[reg] = charge[a];
        tk4[reg] = tok[a];
    }
#pragma unroll
    for (int nt = 0; nt < 4; ++nt) {
        const int cn = (ntb + nt) * 16 + m;
        const float w0 = Wf[cn], w1 = Wf[128 + cn], w2 = Wf[256 + cn],
                    w3 = Wf[384 + cn], bv = bf[cn];
#pragma unroll
        for (int reg = 0; reg < 4; ++reg) {
            const int r = quad * 4 + reg;
            float qv = acc[nt][reg] + px[reg] * w0 + py[reg] * w1 +
                       pz[reg] * w2 + ch[reg] * w3 + bv;
            q_out[(size_t)(a0 + r) * 128 + cn] = qv;
            float cv = qv + s2c[(size_t)tk4[reg] * 128 + cn];
            c_out[(size_t)(a0 + r) * 128 + cn] = cv;
            ctile[r * 136 + cn] = f2bf(fmaxf(cv, 0.f));
        }
    }
    __syncthreads();
    const bfrag* BW = wave ? (const bfrag*)WckF : (const bfrag*)WcqF;
    float* dst = wave ? ack : acq;
    f4 a2 = {0.f, 0.f, 0.f, 0.f};
#pragma unroll
    for (int kb = 0; kb < 4; ++kb) {
        bfrag Af = *(const bfrag*)&ctile[m * 136 + kb * 32 + quad * 8];
        a2 = __builtin_amdgcn_mfma_f32_16x16x32_bf16(Af, BW[kb * 64 + lane],
                                                     a2, 0, 0, 0);
    }
#pragma unroll
    for (int reg = 0; reg < 4; ++reg)
        dst[(size_t)(a0 + quad * 4 + reg) * 16 + m] = a2[reg];
}

// ---------------------------------------------------------------------------
// pair tensor via LDS-free MFMA MLP chain (zp input bf16).
// ---------------------------------------------------------------------------
__global__ __launch_bounds__(256) void pair_mfma_kernel(
    const float* __restrict__ pos, const int* __restrict__ uid,
    const int* __restrict__ tok, const unsigned short* __restrict__ zp_bf,
    const float* __restrict__ acq, const float* __restrict__ ack,
    const float* __restrict__ W_pos, const float* __restrict__ W_dist,
    const float* __restrict__ W_mask, const float* __restrict__ W_m1,
    const float* __restrict__ W_m2, const float* __restrict__ W_m3,
    float* __restrict__ p_out) {
    const int wave = threadIdx.x >> 6, lane = threadIdx.x & 63;
    const int m = lane & 15, quad = lane >> 4;
    const int qa = blockIdx.x * 4 + wave;
    const int j = qa >> 5;

    bfrag A1, A2, A3;
#pragma unroll
    for (int jj = 0; jj < 4; ++jj) {
        const int d = quad * 4 + jj;
        A1[jj] = f2bf(W_m1[d * 16 + m]); A1[jj + 4] = 0;
        A2[jj] = f2bf(W_m2[d * 16 + m]); A2[jj + 4] = 0;
        A3[jj] = f2bf(W_m3[d * 16 + m]); A3[jj + 4] = 0;
    }
    float wp0[4], wp1[4], wp2[4], wd[4], wm[4];
#pragma unroll
    for (int jj = 0; jj < 4; ++jj) {
        const int d = quad * 4 + jj;
        wp0[jj] = W_pos[d]; wp1[jj] = W_pos[16 + d]; wp2[jj] = W_pos[32 + d];
        wd[jj] = W_dist[d]; wm[jj] = W_mask[d];
    }
    const float pqx = pos[qa * 3 + 0], pqy = pos[qa * 3 + 1],
                pqz = pos[qa * 3 + 2];
    const int uq = uid[qa], tq = tok[qa];
    const float4 aq = *(const float4*)(acq + (size_t)qa * 16 + quad * 4);
    const float aqv[4] = {aq.x, aq.y, aq.z, aq.w};
    float* pbase = p_out + (size_t)qa * 2048;

    const f4 zero = {0.f, 0.f, 0.f, 0.f};
#pragma unroll
    for (int g = 0; g < 8; ++g) {
        const int kk = g * 16 + m;
        const int src = j * 32 + kk - 48;
        const bool valid = ((unsigned)src < (unsigned)N_ATOMS);
        float dx = 0.f, dy = 0.f, dz = 0.f, dn = 0.f, vflag = 0.f;
        float zv[4] = {0.f, 0.f, 0.f, 0.f}, av[4] = {0.f, 0.f, 0.f, 0.f};
        if (valid) {
            dx = pos[src * 3 + 0] - pqx;
            dy = pos[src * 3 + 1] - pqy;
            dz = pos[src * 3 + 2] - pqz;
            dn = 1.f / (1.f + dx * dx + dy * dy + dz * dz);
            vflag = (uid[src] == uq) ? 1.f : 0.f;
            const int tk_ = tok[src];
            ushort4 zl = *(const ushort4*)(zp_bf +
                            ((size_t)tq * T_TOK + tk_) * 16 + quad * 4);
            float4 al = *(const float4*)(ack + (size_t)src * 16 + quad * 4);
            zv[0] = bf2f(zl.x); zv[1] = bf2f(zl.y);
            zv[2] = bf2f(zl.z); zv[3] = bf2f(zl.w);
            av[0] = al.x; av[1] = al.y; av[2] = al.z; av[3] = al.w;
        }
        float pb[4];
        bfrag B;
#pragma unroll
        for (int jj = 0; jj < 4; ++jj) {
            float t = dx * wp0[jj] + dy * wp1[jj] + dz * wp2[jj] +
                      dn * wd[jj] + wm[jj];
            pb[jj] = vflag * t + zv[jj] + av[jj] + aqv[jj];
            B[jj] = f2bf(fmaxf(pb[jj], 0.f));
            B[jj + 4] = 0;
        }
        f4 t1 = __builtin_amdgcn_mfma_f32_16x16x32_bf16(A1, B, zero, 0, 0, 0);
        bfrag B2;
#pragma unroll
        for (int jj = 0; jj < 4; ++jj) {
            B2[jj] = f2bf(fmaxf(t1[jj], 0.f)); B2[jj + 4] = 0;
        }
        f4 t2 = __builtin_amdgcn_mfma_f32_16x16x32_bf16(A2, B2, zero, 0, 0, 0);
        bfrag B3;
#pragma unroll
        for (int jj = 0; jj < 4; ++jj) {
            B3[jj] = f2bf(fmaxf(t2[jj], 0.f)); B3[jj + 4] = 0;
        }
        f4 t3 = __builtin_amdgcn_mfma_f32_16x16x32_bf16(A3, B3, zero, 0, 0, 0);
        float4 o = make_float4(pb[0] + t3[0], pb[1] + t3[1],
                               pb[2] + t3[2], pb[3] + t3[3]);
        *(float4*)(pbase + kk * 16 + quad * 4) = o;
    }
}

// ---------------------------------------------------------------------------
extern "C" void kernel_launch(void* const* d_in, const int* in_sizes, int n_in,
                              void* d_out, int out_size, void* d_ws, size_t ws_size,
                              hipStream_t stream) {
    const float* ref_pos     = (const float*)d_in[0];
    const float* ref_charge  = (const float*)d_in[1];
    const float* ref_element = (const float*)d_in[2];
    const float* ref_name    = (const float*)d_in[3];
    const int*   uid         = (const int*)d_in[5];
    const float* a2t         = (const float*)d_in[6];
    const float* s_trunk     = (const float*)d_in[7];
    const float* z           = (const float*)d_in[8];
    const float* W_feat      = (const float*)d_in[9];
    const float* b_feat      = (const float*)d_in[10];
    const float* W_pos       = (const float*)d_in[11];
    const float* W_dist      = (const float*)d_in[12];
    const float* W_mask      = (const float*)d_in[13];
    const float* ln_s_g      = (const float*)d_in[14];
    const float* ln_s_b      = (const float*)d_in[15];
    const float* W_s2c       = (const float*)d_in[16];
    const float* ln_z_g      = (const float*)d_in[17];
    const float* ln_z_b      = (const float*)d_in[18];
    const float* W_z2p       = (const float*)d_in[19];
    const float* W_cq        = (const float*)d_in[20];
    const float* W_ck        = (const float*)d_in[21];
    const float* W_m1        = (const float*)d_in[22];
    const float* W_m2        = (const float*)d_in[23];
    const float* W_m3        = (const float*)d_in[24];

    float* out = (float*)d_out;
    float* q_out = out;                        // 4096*128
    float* c_out = out + 524288;               // 4096*128
    float* p_out = out + 1048576;              // 128*32*128*16

    char* w = (char*)d_ws;
    unsigned short* zp_bf = (unsigned short*)w;      // 4194304 bf16 (8 MB)
    float* s2c  = (float*)(w + 8388608);             // 65536 f32
    float* acq  = s2c + 65536;                       // 65536
    float* ack  = acq + 65536;                       // 65536
    int*   tok  = (int*)(ack + 65536);               // 4096
    short* zpW   = (short*)(tok + 4096);             // 2048
    short* featW = zpW + 2048;                       // 49152
    short* WcqF  = featW + 49152;                    // 2048
    short* WckF  = WcqF + 2048;                      // 2048
    short* s2cW  = WckF + 2048;                      // 49152
    float* bias16 = (float*)(s2cW + 49152);          // 16
    float* cs16   = bias16 + 16;                     // 16
    float* cs128  = cs16 + 16;                       // 128
    float* bs128  = cs128 + 128;                     // 128
    int*   lo     = (int*)(bs128 + 128);             // 512
    int*   hi     = lo + 512;                        // 512
    int*   wl     = hi + 512;                        // 16384+64
    int*   wl_cnt = wl + 16448;                      // 1

    setup_kernel<<<1077, 256, 0, stream>>>(a2t, W_z2p, ln_z_g, ln_z_b,
                                           W_feat, W_cq, W_ck, W_s2c,
                                           ln_s_g, ln_s_b, tok, zpW, featW,
                                           WcqF, WckF, s2cW, bias16, cs16,
                                           cs128, bs128, lo, hi);
    band_kernel<<<16, 256, 0, stream>>>(tok, lo, hi);
    worklist_kernel<<<1, 512, 0, stream>>>(lo, hi, wl, wl_cnt);
    s2c_mfma_kernel<<<64, 256, 0, stream>>>(s_trunk, s2cW, cs128, bs128, s2c);
    zp_wl_kernel<<<512, 256, 0, stream>>>(z, zpW, bias16, cs16, wl, wl_cnt,
                                          zp_bf);
    featcatk_kernel<<<256, 128, 0, stream>>>(ref_pos, ref_charge, ref_element,
                                             ref_name, W_feat, b_feat, s2c, tok,
                                             featW, WcqF, WckF,
                                             q_out, c_out, acq, ack);
    pair_mfma_kernel<<<1024, 256, 0, stream>>>(ref_pos, uid, tok, zp_bf,
                                               acq, ack, W_pos, W_dist, W_mask,
                                               W_m1, W_m2, W_m3, p_out);
}